// Round 1
// baseline (337.738 us; speedup 1.0000x reference)
//
#include <hip/hip_runtime.h>
#include <hip/hip_bf16.h>
#include <cstdint>

#define DEV __device__ __forceinline__

typedef short  s16x8 __attribute__((ext_vector_type(8)));
typedef unsigned short u16x8 __attribute__((ext_vector_type(8)));
typedef float  f32x4 __attribute__((ext_vector_type(4)));
typedef __hip_bfloat16 bf16;

DEV short f2bf(float f) {
    __hip_bfloat16 h = __float2bfloat16(f);
    return __builtin_bit_cast(short, h);
}

// global -> LDS async copy, 16B per lane; LDS base must be wave-uniform.
DEV void gload_lds16(const void* g, void* l) {
    __builtin_amdgcn_global_load_lds(
        (const __attribute__((address_space(1))) uint32_t*)g,
        (__attribute__((address_space(3))) uint32_t*)l, 16, 0, 0);
}

// ---------------------------------------------------------------- prep kernels

// fp32 -> bf16, 8 elems/thread
__global__ void convert_x(const float* __restrict__ in, bf16* __restrict__ out) {
    const int i = (blockIdx.x * 256 + threadIdx.x) * 8;
    f32x4 a = *(const f32x4*)&in[i];
    f32x4 b = *(const f32x4*)&in[i + 4];
    u16x8 o;
#pragma unroll
    for (int j = 0; j < 4; ++j) {
        o[j]     = (unsigned short)f2bf(a[j]);
        o[4 + j] = (unsigned short)f2bf(b[j]);
    }
    *(u16x8*)&out[i] = o;
}

// (768, C) fp32 (G stacked copies at rstride, summed) -> (C, 768) bf16 transpose
template <int G>
__global__ void tconv(const float* __restrict__ in, int C, size_t rstride,
                      bf16* __restrict__ out) {
    __shared__ float t[32][33];
    const int c0 = blockIdx.x * 32, r0 = blockIdx.y * 32;
    const int tx = threadIdx.x & 31, ty = threadIdx.x >> 5;
#pragma unroll
    for (int i = 0; i < 32; i += 8) {
        float s = 0.f;
#pragma unroll
        for (int g = 0; g < G; ++g)
            s += in[g * rstride + (size_t)(r0 + ty + i) * C + c0 + tx];
        t[ty + i][tx] = s;
    }
    __syncthreads();
#pragma unroll
    for (int i = 0; i < 32; i += 8)
        out[(size_t)(c0 + ty + i) * 768 + r0 + tx] = __float2bfloat16(t[tx][ty + i]);
}

// bias_text[o] = sum_r (text_w[r][768][o] + text_b[r][o])   (the concat-ones row)
__global__ void bias_text_k(const float* __restrict__ tw, const float* __restrict__ tb,
                            float* __restrict__ ob) {
    const int o = blockIdx.x * 256 + threadIdx.x;  // grid 3 x 256 = 768 exact
    float s = 0.f;
#pragma unroll
    for (int r = 0; r < 4; ++r)
        s += tw[((size_t)r * 769 + 768) * 768 + o] + tb[r * 768 + o];
    ob[o] = s;
}

// lat_f[b][o] = sum_{i<=768} l1[b][i] * sum_r lat_w[r][i][o] + sum_r lat_b[r][o]
__global__ void latf_k(const float* __restrict__ lat, const float* __restrict__ lw,
                       const float* __restrict__ lb, float* __restrict__ latf) {
    const int b  = blockIdx.y;
    const int o  = blockIdx.x * 32 + (threadIdx.x >> 3);
    const int ip = threadIdx.x & 7;
    float s = 0.f;
    for (int i = ip; i < 769; i += 8) {
        float coef = (i < 768) ? lat[b * 768 + i] : 1.0f;  // concat-ones row
        float wsum = 0.f;
#pragma unroll
        for (int r = 0; r < 4; ++r) wsum += lw[((size_t)r * 769 + i) * 768 + o];
        s += coef * wsum;
    }
    s += __shfl_xor(s, 1);
    s += __shfl_xor(s, 2);
    s += __shfl_xor(s, 4);
    if (ip == 0) {
        float bb = 0.f;
#pragma unroll
        for (int r = 0; r < 4; ++r) bb += lb[r * 768 + o];
        latf[b * 768 + o] = s + bb;
    }
}

// V part of qkv (cols 1536..2303) -> vT[bh][d][s]  (bf16 raw u16 copy)
__global__ void vtrans_k(const unsigned short* __restrict__ qkv,
                         unsigned short* __restrict__ vT) {
    __shared__ unsigned short t[64][72];  // 144B rows: 16B-aligned, spread banks
    const int bh = blockIdx.y, b = bh / 12, h = bh - b * 12;
    const int s0 = blockIdx.x * 64;
    const int tr = threadIdx.x >> 3, tc = (threadIdx.x & 7) * 8;
#pragma unroll
    for (int p = 0; p < 2; ++p) {
        int sr = tr + p * 32;
        *(u16x8*)&t[sr][tc] =
            *(const u16x8*)&qkv[(size_t)(b * 2048 + s0 + sr) * 2304 + 1536 + h * 64 + tc];
    }
    __syncthreads();
#pragma unroll
    for (int p = 0; p < 2; ++p) {
        int d = tr + p * 32;
        u16x8 v;
#pragma unroll
        for (int j = 0; j < 8; ++j) v[j] = t[tc + j][d];
        *(u16x8*)&vT[((size_t)bh * 64 + d) * 2048 + s0 + tc] = v;
    }
}

// ---------------------------------------------------------------- GEMM (m97 structure)
// C[M,N] = A[M,K] @ Bt[N,K]^T ; 128x128 tile, BK=32, 4 waves x 64x64, 16x16x32 bf16 MFMA.
// EPI 0: +bias -> bf16 (ldc=2304, qkv)   EPI 1: (acc+bias)*latf*0.125 -> bf16 (fused q)
// EPI 2: +bias -> f32 (final out)
template <int EPI>
__global__ __launch_bounds__(256) void gemm_bt(
    const bf16* __restrict__ A, int lda, const bf16* __restrict__ Bt,
    const float* __restrict__ bias, const float* __restrict__ latf,
    void* __restrict__ Cout, int ldc, int K) {
    __shared__ bf16 Al[128 * 32];
    __shared__ bf16 Bl[128 * 32];
    const int tid = threadIdx.x, w = tid >> 6, lane = tid & 63;
    const int row0 = blockIdx.x * 128, col0 = blockIdx.y * 128;
    const int wm = (w >> 1) * 64, wn = (w & 1) * 64;
    const int lr = lane & 15, lk8 = (lane >> 4) * 8, lq = lane >> 4;
    const int sr = lane >> 2;        // staging: row within 16-row chunk
    const int sc = (lane & 3) * 8;   // staging: 8-elem (16B) column offset
    f32x4 acc[4][4] = {};
    for (int k0 = 0; k0 < K; k0 += 32) {
#pragma unroll
        for (int i = 0; i < 2; ++i) {
            const int rr = w * 32 + i * 16;  // wave-uniform LDS chunk base
            gload_lds16(A  + (size_t)(row0 + rr + sr) * lda + k0 + sc, &Al[rr * 32]);
            gload_lds16(Bt + (size_t)(col0 + rr + sr) * K   + k0 + sc, &Bl[rr * 32]);
        }
        __syncthreads();
        s16x8 af[4], bfr[4];
#pragma unroll
        for (int m = 0; m < 4; ++m) af[m]  = *(const s16x8*)&Al[(wm + m * 16 + lr) * 32 + lk8];
#pragma unroll
        for (int n = 0; n < 4; ++n) bfr[n] = *(const s16x8*)&Bl[(wn + n * 16 + lr) * 32 + lk8];
#pragma unroll
        for (int m = 0; m < 4; ++m)
#pragma unroll
            for (int n = 0; n < 4; ++n)
                acc[m][n] = __builtin_amdgcn_mfma_f32_16x16x32_bf16(af[m], bfr[n], acc[m][n], 0, 0, 0);
        __syncthreads();
    }
#pragma unroll
    for (int m = 0; m < 4; ++m)
#pragma unroll
        for (int n = 0; n < 4; ++n)
#pragma unroll
            for (int r = 0; r < 4; ++r) {
                const int row = row0 + wm + m * 16 + lq * 4 + r;  // D: row=(l>>4)*4+r
                const int col = col0 + wn + n * 16 + lr;          //    col=l&15
                const float v = acc[m][n][r];
                if (EPI == 0) {
                    ((bf16*)Cout)[(size_t)row * ldc + col] = __float2bfloat16(v + bias[col]);
                } else if (EPI == 1) {
                    ((bf16*)Cout)[(size_t)row * ldc + col] = __float2bfloat16(
                        (v + bias[col]) * latf[(row >> 11) * 768 + col] * 0.125f);
                } else {
                    ((float*)Cout)[(size_t)row * ldc + col] = v + bias[col];
                }
            }
}

// ---------------------------------------------------------------- flash attention
// grid (32, 12): blockIdx.x*128 = q-row block over 4096 rows, blockIdx.y = head.
// 4 independent waves/block, 32 q-rows each; 64-key KV tiles; K/V frags straight
// from global (KV is L2-resident); P transposed via per-wave padded LDS buffer.
__global__ __launch_bounds__(256) void attn_k(
    const bf16* __restrict__ qf, const bf16* __restrict__ qkv,
    const bf16* __restrict__ vT, bf16* __restrict__ aout) {
    __shared__ float P[4][32][68];
    const int w = threadIdx.x >> 6, lane = threadIdx.x & 63;
    const int h = blockIdx.y;
    const int brow = blockIdx.x * 128 + w * 32;  // row in [0,4096)
    const int b = brow >> 11;
    const int qpos = brow & 2047;                // sequence position of first row
    const int bh = b * 12 + h;
    const int lr = lane & 15, lk8 = (lane >> 4) * 8, lq = lane >> 4;
    float(*Pw)[68] = P[w];

    s16x8 qa[2][2];
#pragma unroll
    for (int m = 0; m < 2; ++m)
#pragma unroll
        for (int ks = 0; ks < 2; ++ks)
            qa[m][ks] = *(const s16x8*)&qf[(size_t)(brow + m * 16 + lr) * 768 + h * 64 + ks * 32 + lk8];

    float mrun[2][4], lrun[2][4];
    f32x4 oacc[2][4] = {};
#pragma unroll
    for (int m = 0; m < 2; ++m)
#pragma unroll
        for (int r = 0; r < 4; ++r) { mrun[m][r] = -3.0e38f; lrun[m][r] = 0.f; }

    const int nt = (qpos + 95) >> 6;       // number of 64-key tiles (causal)
    const bf16* Kb = qkv + 768 + h * 64;   // K part of qkv
    for (int t = 0; t < nt; ++t) {
        const int kv0 = t * 64;
        f32x4 s[2][4] = {};
#pragma unroll
        for (int ks = 0; ks < 2; ++ks) {
            s16x8 kb[4];
#pragma unroll
            for (int n = 0; n < 4; ++n)
                kb[n] = *(const s16x8*)&Kb[(size_t)(b * 2048 + kv0 + n * 16 + lr) * 2304 + ks * 32 + lk8];
#pragma unroll
            for (int m = 0; m < 2; ++m)
#pragma unroll
                for (int n = 0; n < 4; ++n)
                    s[m][n] = __builtin_amdgcn_mfma_f32_16x16x32_bf16(qa[m][ks], kb[n], s[m][n], 0, 0, 0);
        }
        if (t == nt - 1) {  // only the last tile can cross the diagonal
#pragma unroll
            for (int m = 0; m < 2; ++m)
#pragma unroll
                for (int n = 0; n < 4; ++n)
#pragma unroll
                    for (int r = 0; r < 4; ++r)
                        if (kv0 + n * 16 + lr > qpos + m * 16 + lq * 4 + r)
                            s[m][n][r] = -10000.0f;
        }
        // online softmax; rows live in 16-lane column groups -> shfl_xor 1/2/4/8
#pragma unroll
        for (int m = 0; m < 2; ++m)
#pragma unroll
            for (int r = 0; r < 4; ++r) {
                float v = fmaxf(fmaxf(s[m][0][r], s[m][1][r]), fmaxf(s[m][2][r], s[m][3][r]));
                v = fmaxf(v, __shfl_xor(v, 1));
                v = fmaxf(v, __shfl_xor(v, 2));
                v = fmaxf(v, __shfl_xor(v, 4));
                v = fmaxf(v, __shfl_xor(v, 8));
                const float newm = fmaxf(mrun[m][r], v);
                const float sc = __expf(mrun[m][r] - newm);
                mrun[m][r] = newm;
                float rs = 0.f;
#pragma unroll
                for (int n = 0; n < 4; ++n) {
                    float p = __expf(s[m][n][r] - newm);
                    s[m][n][r] = p;
                    rs += p;
                }
                rs += __shfl_xor(rs, 1);
                rs += __shfl_xor(rs, 2);
                rs += __shfl_xor(rs, 4);
                rs += __shfl_xor(rs, 8);
                lrun[m][r] = lrun[m][r] * sc + rs;
#pragma unroll
                for (int dn = 0; dn < 4; ++dn) oacc[m][dn][r] *= sc;
            }
        // P (D-layout) -> LDS -> A-layout frags
#pragma unroll
        for (int m = 0; m < 2; ++m)
#pragma unroll
            for (int n = 0; n < 4; ++n)
#pragma unroll
                for (int r = 0; r < 4; ++r)
                    Pw[m * 16 + lq * 4 + r][n * 16 + lr] = s[m][n][r];
#pragma unroll
        for (int ks = 0; ks < 2; ++ks) {
            s16x8 pa[2];
#pragma unroll
            for (int am = 0; am < 2; ++am) {
                const float* pp = &Pw[am * 16 + lr][ks * 32 + lk8];
                f32x4 p0 = *(const f32x4*)pp;
                f32x4 p1 = *(const f32x4*)(pp + 4);
                s16x8 pb;
#pragma unroll
                for (int e = 0; e < 4; ++e) { pb[e] = f2bf(p0[e]); pb[4 + e] = f2bf(p1[e]); }
                pa[am] = pb;
            }
            s16x8 vb[4];
#pragma unroll
            for (int dn = 0; dn < 4; ++dn)
                vb[dn] = *(const s16x8*)&vT[((size_t)bh * 64 + dn * 16 + lr) * 2048 + kv0 + ks * 32 + lk8];
#pragma unroll
            for (int am = 0; am < 2; ++am)
#pragma unroll
                for (int dn = 0; dn < 4; ++dn)
                    oacc[am][dn] = __builtin_amdgcn_mfma_f32_16x16x32_bf16(pa[am], vb[dn], oacc[am][dn], 0, 0, 0);
        }
    }
#pragma unroll
    for (int m = 0; m < 2; ++m)
#pragma unroll
        for (int dn = 0; dn < 4; ++dn)
#pragma unroll
            for (int r = 0; r < 4; ++r)
                aout[(size_t)(brow + m * 16 + lq * 4 + r) * 768 + h * 64 + dn * 16 + lr] =
                    __float2bfloat16(oacc[m][dn][r] / lrun[m][r]);
}

// ---------------------------------------------------------------- launch

extern "C" void kernel_launch(void* const* d_in, const int* in_sizes, int n_in,
                              void* d_out, int out_size, void* d_ws, size_t ws_size,
                              hipStream_t stream) {
    (void)in_sizes; (void)n_in; (void)out_size; (void)ws_size;
    const float* x      = (const float*)d_in[0];
    const float* lat    = (const float*)d_in[1];
    const float* attn_w = (const float*)d_in[2];
    const float* attn_b = (const float*)d_in[3];
    const float* proj_w = (const float*)d_in[4];
    const float* proj_b = (const float*)d_in[5];
    const float* text_w = (const float*)d_in[6];
    const float* text_b = (const float*)d_in[7];
    const float* lat_w  = (const float*)d_in[8];
    const float* lat_b  = (const float*)d_in[9];
    float* out = (float*)d_out;

    char* ws = (char*)d_ws;
    size_t off = 0;
    auto take = [&](size_t bytes) -> char* {
        char* p = ws + off;
        off = (off + bytes + 255) & ~(size_t)255;
        return p;
    };
    bf16* x_bf   = (bf16*)take(4096ul * 768 * 2);
    bf16* awT    = (bf16*)take(2304ul * 768 * 2);   // c_attn_w^T
    bf16* pwT    = (bf16*)take(768ul * 768 * 2);    // c_proj_w^T
    bf16* twT    = (bf16*)take(768ul * 768 * 2);    // sum_r lmf_text_w^T (first 768 rows)
    bf16* qkv_bf = (bf16*)take(4096ul * 2304 * 2);
    bf16* qf_bf  = (bf16*)take(4096ul * 768 * 2);   // fused+prescaled q
    bf16* vT     = (bf16*)take(24ul * 64 * 2048 * 2);
    bf16* a_bf   = (bf16*)take(4096ul * 768 * 2);
    float* tbias = (float*)take(768 * 4);
    float* latf  = (float*)take(2 * 768 * 4);

    convert_x<<<1536, 256, 0, stream>>>(x, x_bf);
    tconv<1><<<dim3(72, 24), 256, 0, stream>>>(attn_w, 2304, 0, awT);
    tconv<1><<<dim3(24, 24), 256, 0, stream>>>(proj_w, 768, 0, pwT);
    tconv<4><<<dim3(24, 24), 256, 0, stream>>>(text_w, 768, 769ul * 768, twT);
    bias_text_k<<<3, 256, 0, stream>>>(text_w, text_b, tbias);
    latf_k<<<dim3(24, 2), 256, 0, stream>>>(lat, lat_w, lat_b, latf);

    gemm_bt<0><<<dim3(32, 18), 256, 0, stream>>>(x_bf, 768, awT, attn_b, nullptr, qkv_bf, 2304, 768);
    vtrans_k<<<dim3(32, 24), 256, 0, stream>>>((const unsigned short*)qkv_bf, (unsigned short*)vT);
    gemm_bt<1><<<dim3(32, 6), 256, 0, stream>>>(qkv_bf, 2304, twT, tbias, latf, qf_bf, 768, 768);
    attn_k<<<dim3(32, 12), 256, 0, stream>>>(qf_bf, qkv_bf, vT, a_bf);
    gemm_bt<2><<<dim3(32, 6), 256, 0, stream>>>(a_bf, 768, pwT, proj_b, nullptr, out, 768, 768);
}

// Round 2
// 300.456 us; speedup vs baseline: 1.1241x; 1.1241x over previous
//
#include <hip/hip_runtime.h>
#include <hip/hip_bf16.h>
#include <cstdint>

#define DEV __device__ __forceinline__

typedef short  s16x8 __attribute__((ext_vector_type(8)));
typedef unsigned short u16x8 __attribute__((ext_vector_type(8)));
typedef float  f32x4 __attribute__((ext_vector_type(4)));
typedef __hip_bfloat16 bf16;

DEV short f2bf(float f) {
    __hip_bfloat16 h = __float2bfloat16(f);
    return __builtin_bit_cast(short, h);
}

// global -> LDS async copy, 16B per lane; LDS base must be wave-uniform.
DEV void gload_lds16(const void* g, void* l) {
    __builtin_amdgcn_global_load_lds(
        (const __attribute__((address_space(1))) uint32_t*)g,
        (__attribute__((address_space(3))) uint32_t*)l, 16, 0, 0);
}

// ---------------------------------------------------------------- prep kernels

// fp32 -> bf16, 8 elems/thread
__global__ void convert_x(const float* __restrict__ in, bf16* __restrict__ out) {
    const int i = (blockIdx.x * 256 + threadIdx.x) * 8;
    f32x4 a = *(const f32x4*)&in[i];
    f32x4 b = *(const f32x4*)&in[i + 4];
    u16x8 o;
#pragma unroll
    for (int j = 0; j < 4; ++j) {
        o[j]     = (unsigned short)f2bf(a[j]);
        o[4 + j] = (unsigned short)f2bf(b[j]);
    }
    *(u16x8*)&out[i] = o;
}

// All three weight transposes in one launch. z=0: attn_w (768x2304), z=1: proj_w
// (768x768), z=2: sum_r text_w (769x768, first 768 rows). out is (C,768) bf16.
__global__ void tconv_all(const float* __restrict__ aw, const float* __restrict__ pw,
                          const float* __restrict__ tw, bf16* __restrict__ awT,
                          bf16* __restrict__ pwT, bf16* __restrict__ twT) {
    __shared__ float t[32][33];
    const int z = blockIdx.z;
    const float* in; bf16* out; int C, G; size_t rstr;
    if (z == 0)      { in = aw; out = awT; C = 2304; G = 1; rstr = 0; }
    else if (z == 1) { in = pw; out = pwT; C = 768;  G = 1; rstr = 0; }
    else             { in = tw; out = twT; C = 768;  G = 4; rstr = 769ul * 768; }
    const int c0 = blockIdx.x * 32, r0 = blockIdx.y * 32;
    if (c0 >= C) return;
    const int tx = threadIdx.x & 31, ty = threadIdx.x >> 5;
#pragma unroll
    for (int i = 0; i < 32; i += 8) {
        float s = 0.f;
        for (int g = 0; g < G; ++g)
            s += in[g * rstr + (size_t)(r0 + ty + i) * C + c0 + tx];
        t[ty + i][tx] = s;
    }
    __syncthreads();
#pragma unroll
    for (int i = 0; i < 32; i += 8)
        out[(size_t)(c0 + ty + i) * 768 + r0 + tx] = __float2bfloat16(t[tx][ty + i]);
}

// bias_text[o] = sum_r (text_w[r][768][o] + text_b[r][o])   (the concat-ones row)
__global__ void bias_text_k(const float* __restrict__ tw, const float* __restrict__ tb,
                            float* __restrict__ ob) {
    const int o = blockIdx.x * 256 + threadIdx.x;  // grid 3 x 256 = 768 exact
    float s = 0.f;
#pragma unroll
    for (int r = 0; r < 4; ++r)
        s += tw[((size_t)r * 769 + 768) * 768 + o] + tb[r * 768 + o];
    ob[o] = s;
}

// lat_f[b][o] = sum_{i<=768} l1[b][i] * sum_r lat_w[r][i][o] + sum_r lat_b[r][o]
__global__ void latf_k(const float* __restrict__ lat, const float* __restrict__ lw,
                       const float* __restrict__ lb, float* __restrict__ latf) {
    const int b  = blockIdx.y;
    const int o  = blockIdx.x * 32 + (threadIdx.x >> 3);
    const int ip = threadIdx.x & 7;
    float s = 0.f;
    for (int i = ip; i < 769; i += 8) {
        float coef = (i < 768) ? lat[b * 768 + i] : 1.0f;  // concat-ones row
        float wsum = 0.f;
#pragma unroll
        for (int r = 0; r < 4; ++r) wsum += lw[((size_t)r * 769 + i) * 768 + o];
        s += coef * wsum;
    }
    s += __shfl_xor(s, 1);
    s += __shfl_xor(s, 2);
    s += __shfl_xor(s, 4);
    if (ip == 0) {
        float bb = 0.f;
#pragma unroll
        for (int r = 0; r < 4; ++r) bb += lb[r * 768 + o];
        latf[b * 768 + o] = s + bb;
    }
}

// V part of qkv (cols 1536..2303) -> vT[bh][d][s]  (bf16 raw u16 copy)
__global__ void vtrans_k(const unsigned short* __restrict__ qkv,
                         unsigned short* __restrict__ vT) {
    __shared__ unsigned short t[64][72];  // 144B rows: 16B-aligned, spread banks
    const int bh = blockIdx.y, b = bh / 12, h = bh - b * 12;
    const int s0 = blockIdx.x * 64;
    const int tr = threadIdx.x >> 3, tc = (threadIdx.x & 7) * 8;
#pragma unroll
    for (int p = 0; p < 2; ++p) {
        int sr = tr + p * 32;
        *(u16x8*)&t[sr][tc] =
            *(const u16x8*)&qkv[(size_t)(b * 2048 + s0 + sr) * 2304 + 1536 + h * 64 + tc];
    }
    __syncthreads();
#pragma unroll
    for (int p = 0; p < 2; ++p) {
        int d = tr + p * 32;
        u16x8 v;
#pragma unroll
        for (int j = 0; j < 8; ++j) v[j] = t[tc + j][d];
        *(u16x8*)&vT[((size_t)bh * 64 + d) * 2048 + s0 + tc] = v;
    }
}

// ---------------------------------------------------------------- GEMM (m97 structure)
// C[M,N] = A[M,K] @ Bt[N,K]^T ; 128xTN tile, BK=32, 4 waves, 16x16x32 bf16 MFMA.
// EPI 0: +bias -> bf16 (ldc=2304, qkv)   EPI 1: (acc+bias)*latf*0.125 -> bf16 (fused q)
// EPI 2: +bias -> f32 (final out)
template <int EPI, int TN>
__global__ __launch_bounds__(256) void gemm_bt(
    const bf16* __restrict__ A, int lda, const bf16* __restrict__ Bt,
    const float* __restrict__ bias, const float* __restrict__ latf,
    void* __restrict__ Cout, int ldc, int K) {
    constexpr int FN = TN / 32;  // 16-wide B tiles per wave
    __shared__ bf16 Al[128 * 32];
    __shared__ bf16 Bl[TN * 32];
    const int tid = threadIdx.x, w = tid >> 6, lane = tid & 63;
    const int row0 = blockIdx.x * 128, col0 = blockIdx.y * TN;
    const int wm = (w >> 1) * 64, wn = (w & 1) * (TN / 2);
    const int lr = lane & 15, lk8 = (lane >> 4) * 8, lq = lane >> 4;
    const int sr = lane >> 2;        // staging: row within 16-row chunk
    const int sc = (lane & 3) * 8;   // staging: 8-elem (16B) column offset
    f32x4 acc[4][FN] = {};
    for (int k0 = 0; k0 < K; k0 += 32) {
#pragma unroll
        for (int i = 0; i < 2; ++i) {
            const int rr = w * 32 + i * 16;  // wave-uniform LDS chunk base
            gload_lds16(A + (size_t)(row0 + rr + sr) * lda + k0 + sc, &Al[rr * 32]);
        }
#pragma unroll
        for (int i = 0; i < TN / 64; ++i) {
            const int rb = (w * (TN / 64) + i) * 16;
            gload_lds16(Bt + (size_t)(col0 + rb + sr) * K + k0 + sc, &Bl[rb * 32]);
        }
        __syncthreads();
        s16x8 af[4], bfr[FN];
#pragma unroll
        for (int m = 0; m < 4; ++m) af[m]  = *(const s16x8*)&Al[(wm + m * 16 + lr) * 32 + lk8];
#pragma unroll
        for (int n = 0; n < FN; ++n) bfr[n] = *(const s16x8*)&Bl[(wn + n * 16 + lr) * 32 + lk8];
        __builtin_amdgcn_s_setprio(1);
#pragma unroll
        for (int m = 0; m < 4; ++m)
#pragma unroll
            for (int n = 0; n < FN; ++n)
                acc[m][n] = __builtin_amdgcn_mfma_f32_16x16x32_bf16(af[m], bfr[n], acc[m][n], 0, 0, 0);
        __builtin_amdgcn_s_setprio(0);
        __syncthreads();
    }
#pragma unroll
    for (int m = 0; m < 4; ++m)
#pragma unroll
        for (int n = 0; n < FN; ++n)
#pragma unroll
            for (int r = 0; r < 4; ++r) {
                const int row = row0 + wm + m * 16 + lq * 4 + r;  // D: row=(l>>4)*4+r
                const int col = col0 + wn + n * 16 + lr;          //    col=l&15
                const float v = acc[m][n][r];
                if (EPI == 0) {
                    ((bf16*)Cout)[(size_t)row * ldc + col] = __float2bfloat16(v + bias[col]);
                } else if (EPI == 1) {
                    ((bf16*)Cout)[(size_t)row * ldc + col] = __float2bfloat16(
                        (v + bias[col]) * latf[(row >> 11) * 768 + col] * 0.125f);
                } else {
                    ((float*)Cout)[(size_t)row * ldc + col] = v + bias[col];
                }
            }
}

// ---------------------------------------------------------------- flash attention
// 256 blocks x 6 waves = 1536 wave-tasks. Each wave handles a diagonal PAIR of
// 16-row q-tiles (p, 127-p) of one (b,h) => uniform ~34 KV-tiles per wave (no
// tail imbalance). K double-buffered in regs (prefetch next tile during softmax),
// V loads hoisted to tile top. Per-lane partial row-sums, reduced once at end.
// XCD swizzle: all tasks of a (b,h) land on one XCD's L2 (KV set 3MB < 4MB).
__global__ __launch_bounds__(384) void attn_k(
    const bf16* __restrict__ qf, const bf16* __restrict__ qkv,
    const bf16* __restrict__ vT, bf16* __restrict__ aout) {
    __shared__ float P[6][16][68];
    const int w = threadIdx.x / 64, lane = threadIdx.x & 63;
    const int lb = (blockIdx.x & 7) * 32 + (blockIdx.x >> 3);  // XCD-cluster swizzle
    const int task = lb * 6 + w;               // 0..1535
    const int bh = task >> 6, pr = task & 63;  // head-task, pair index
    const int b = bh / 12, h = bh - b * 12;
    const int lr = lane & 15, lq = lane >> 4, lk8 = (lane >> 4) * 8;
    float (*Pw)[68] = P[w];
    const bf16* Kb = qkv + (size_t)b * 2048 * 2304 + 768 + h * 64;
    const bf16* Vb = vT + (size_t)bh * 64 * 2048;

#define LOADK(T, DST)                                                                   \
    do {                                                                                \
        const int kv0_ = (T) * 64;                                                      \
        _Pragma("unroll") for (int ks = 0; ks < 2; ++ks)                                \
            _Pragma("unroll") for (int n = 0; n < 4; ++n)                               \
                DST[ks][n] = *(const s16x8*)&Kb[(size_t)(kv0_ + n * 16 + lr) * 2304 +   \
                                                ks * 32 + lk8];                         \
    } while (0)

#define BODY(kc, kn)                                                                    \
    do {                                                                                \
        const int kv0 = t * 64;                                                         \
        s16x8 vb[2][4];                                                                 \
        _Pragma("unroll") for (int ks = 0; ks < 2; ++ks)                                \
            _Pragma("unroll") for (int dn = 0; dn < 4; ++dn)                            \
                vb[ks][dn] = *(const s16x8*)&Vb[(size_t)(dn * 16 + lr) * 2048 + kv0 +   \
                                                ks * 32 + lk8];                         \
        f32x4 st[4] = {};                                                               \
        __builtin_amdgcn_s_setprio(1);                                                  \
        _Pragma("unroll") for (int ks = 0; ks < 2; ++ks)                                \
            _Pragma("unroll") for (int n = 0; n < 4; ++n)                               \
                st[n] = __builtin_amdgcn_mfma_f32_16x16x32_bf16(qa[ks], kc[ks][n],      \
                                                                st[n], 0, 0, 0);        \
        __builtin_amdgcn_s_setprio(0);                                                  \
        if (t + 1 < nt) LOADK(t + 1, kn);                                               \
        if (t == nt - 1) {                                                              \
            _Pragma("unroll") for (int n = 0; n < 4; ++n)                               \
                _Pragma("unroll") for (int r = 0; r < 4; ++r)                           \
                    if (kv0 + n * 16 + lr > qpos + lq * 4 + r) st[n][r] = -10000.0f;    \
        }                                                                               \
        _Pragma("unroll") for (int r = 0; r < 4; ++r) {                                 \
            float v = fmaxf(fmaxf(st[0][r], st[1][r]), fmaxf(st[2][r], st[3][r]));      \
            v = fmaxf(v, __shfl_xor(v, 1));                                             \
            v = fmaxf(v, __shfl_xor(v, 2));                                             \
            v = fmaxf(v, __shfl_xor(v, 4));                                             \
            v = fmaxf(v, __shfl_xor(v, 8));                                             \
            const float newm = fmaxf(mr[r], v);                                         \
            const float scl = __expf(mr[r] - newm);                                     \
            mr[r] = newm;                                                               \
            float ps = 0.f;                                                             \
            _Pragma("unroll") for (int n = 0; n < 4; ++n) {                             \
                float p = __expf(st[n][r] - newm);                                      \
                st[n][r] = p;                                                           \
                ps += p;                                                                \
            }                                                                           \
            lsum[r] = lsum[r] * scl + ps;  /* per-lane partial, reduced at end */       \
            _Pragma("unroll") for (int dn = 0; dn < 4; ++dn) oacc[dn][r] *= scl;        \
        }                                                                               \
        _Pragma("unroll") for (int n = 0; n < 4; ++n)                                   \
            _Pragma("unroll") for (int r = 0; r < 4; ++r)                               \
                Pw[lq * 4 + r][n * 16 + lr] = st[n][r];                                 \
        _Pragma("unroll") for (int ks = 0; ks < 2; ++ks) {                              \
            const float* pp = &Pw[lr][ks * 32 + lk8];                                   \
            f32x4 p0 = *(const f32x4*)pp;                                               \
            f32x4 p1 = *(const f32x4*)(pp + 4);                                         \
            s16x8 pa;                                                                   \
            _Pragma("unroll") for (int e = 0; e < 4; ++e) {                             \
                pa[e] = f2bf(p0[e]);                                                    \
                pa[4 + e] = f2bf(p1[e]);                                                \
            }                                                                           \
            __builtin_amdgcn_s_setprio(1);                                              \
            _Pragma("unroll") for (int dn = 0; dn < 4; ++dn)                            \
                oacc[dn] = __builtin_amdgcn_mfma_f32_16x16x32_bf16(pa, vb[ks][dn],      \
                                                                   oacc[dn], 0, 0, 0); \
            __builtin_amdgcn_s_setprio(0);                                              \
        }                                                                               \
    } while (0)

    auto runTile = [&](int p) {
        const int qpos = p * 16;
        const size_t grow = (size_t)b * 2048 + qpos;
        s16x8 qa[2];
#pragma unroll
        for (int ks = 0; ks < 2; ++ks)
            qa[ks] = *(const s16x8*)&qf[(grow + lr) * 768 + h * 64 + ks * 32 + lk8];
        float mr[4], lsum[4];
        f32x4 oacc[4];
#pragma unroll
        for (int r = 0; r < 4; ++r) { mr[r] = -3.0e38f; lsum[r] = 0.f; oacc[r] = f32x4{}; }
        const int nt = (qpos + 79) >> 6;  // KV tiles needed (causal, 16 rows)
        s16x8 kA[2][4], kB[2][4];
        LOADK(0, kA);
        int t = 0;
        while (true) {
            BODY(kA, kB);
            if (++t == nt) break;
            BODY(kB, kA);
            if (++t == nt) break;
        }
#pragma unroll
        for (int r = 0; r < 4; ++r) {
            float ls = lsum[r];
            ls += __shfl_xor(ls, 1);
            ls += __shfl_xor(ls, 2);
            ls += __shfl_xor(ls, 4);
            ls += __shfl_xor(ls, 8);
            const float inv = 1.0f / ls;
#pragma unroll
            for (int dn = 0; dn < 4; ++dn)
                aout[(grow + lq * 4 + r) * 768 + h * 64 + dn * 16 + lr] =
                    __float2bfloat16(oacc[dn][r] * inv);
        }
    };

    runTile(pr);        // light tile (qpos = 16*pr)
    runTile(127 - pr);  // heavy tile — pair sums to uniform work
#undef BODY
#undef LOADK
}

// ---------------------------------------------------------------- launch

extern "C" void kernel_launch(void* const* d_in, const int* in_sizes, int n_in,
                              void* d_out, int out_size, void* d_ws, size_t ws_size,
                              hipStream_t stream) {
    (void)in_sizes; (void)n_in; (void)out_size; (void)ws_size;
    const float* x      = (const float*)d_in[0];
    const float* lat    = (const float*)d_in[1];
    const float* attn_w = (const float*)d_in[2];
    const float* attn_b = (const float*)d_in[3];
    const float* proj_w = (const float*)d_in[4];
    const float* proj_b = (const float*)d_in[5];
    const float* text_w = (const float*)d_in[6];
    const float* text_b = (const float*)d_in[7];
    const float* lat_w  = (const float*)d_in[8];
    const float* lat_b  = (const float*)d_in[9];
    float* out = (float*)d_out;

    char* ws = (char*)d_ws;
    size_t off = 0;
    auto take = [&](size_t bytes) -> char* {
        char* p = ws + off;
        off = (off + bytes + 255) & ~(size_t)255;
        return p;
    };
    bf16* x_bf   = (bf16*)take(4096ul * 768 * 2);
    bf16* awT    = (bf16*)take(2304ul * 768 * 2);   // c_attn_w^T
    bf16* pwT    = (bf16*)take(768ul * 768 * 2);    // c_proj_w^T
    bf16* twT    = (bf16*)take(768ul * 768 * 2);    // sum_r lmf_text_w^T (first 768 rows)
    bf16* qkv_bf = (bf16*)take(4096ul * 2304 * 2);
    bf16* qf_bf  = (bf16*)take(4096ul * 768 * 2);   // fused+prescaled q
    bf16* vT     = (bf16*)take(24ul * 64 * 2048 * 2);
    bf16* a_bf   = (bf16*)take(4096ul * 768 * 2);
    float* tbias = (float*)take(768 * 4);
    float* latf  = (float*)take(2 * 768 * 4);

    convert_x<<<1536, 256, 0, stream>>>(x, x_bf);
    tconv_all<<<dim3(72, 24, 3), 256, 0, stream>>>(attn_w, proj_w, text_w, awT, pwT, twT);
    bias_text_k<<<3, 256, 0, stream>>>(text_w, text_b, tbias);
    latf_k<<<dim3(24, 2), 256, 0, stream>>>(lat, lat_w, lat_b, latf);

    gemm_bt<0, 128><<<dim3(32, 18), 256, 0, stream>>>(x_bf, 768, awT, attn_b, nullptr, qkv_bf, 2304, 768);
    vtrans_k<<<dim3(32, 24), 256, 0, stream>>>((const unsigned short*)qkv_bf, (unsigned short*)vT);
    gemm_bt<1, 64><<<dim3(32, 12), 256, 0, stream>>>(qkv_bf, 2304, twT, tbias, latf, qf_bf, 768, 768);
    attn_k<<<256, 384, 0, stream>>>(qf_bf, qkv_bf, vT, a_bf);
    gemm_bt<2, 64><<<dim3(32, 12), 256, 0, stream>>>(a_bf, 768, pwT, proj_b, nullptr, out, 768, 768);
}

// Round 5
// 294.354 us; speedup vs baseline: 1.1474x; 1.0207x over previous
//
#include <hip/hip_runtime.h>
#include <hip/hip_bf16.h>
#include <cstdint>

#define DEV __device__ __forceinline__

typedef short  s16x8 __attribute__((ext_vector_type(8)));
typedef short  s16x4 __attribute__((ext_vector_type(4)));
typedef unsigned short u16x8 __attribute__((ext_vector_type(8)));
typedef float  f32x4 __attribute__((ext_vector_type(4)));
typedef __hip_bfloat16 bf16;

DEV short f2bf(float f) {
    __hip_bfloat16 h = __float2bfloat16(f);
    return __builtin_bit_cast(short, h);
}

DEV f32x4 vmax4(f32x4 a, f32x4 b) {
    f32x4 r;
#pragma unroll
    for (int j = 0; j < 4; ++j) r[j] = fmaxf(a[j], b[j]);
    return r;
}

// global -> LDS async copy, 16B per lane; LDS base must be wave-uniform.
DEV void gload_lds16(const void* g, void* l) {
    __builtin_amdgcn_global_load_lds(
        (const __attribute__((address_space(1))) uint32_t*)g,
        (__attribute__((address_space(3))) uint32_t*)l, 16, 0, 0);
}

// ---------------------------------------------------------------- prep (one launch)
// z=0: attn_w^T (768x2304->T)  z=1: proj_w^T  z=2: sum_r text_w^T
// z=3: bias_text (x<3) + latf (3<=x<51)   z=4: x fp32->bf16
__global__ void prep_all(const float* __restrict__ x, const float* __restrict__ aw,
                         const float* __restrict__ pw, const float* __restrict__ tw,
                         const float* __restrict__ tb, const float* __restrict__ lat,
                         const float* __restrict__ lw, const float* __restrict__ lb,
                         bf16* __restrict__ x_bf, bf16* __restrict__ awT,
                         bf16* __restrict__ pwT, bf16* __restrict__ twT,
                         float* __restrict__ tbias, float* __restrict__ latf) {
    const int z = blockIdx.z;
    if (z == 4) {  // convert x
        const int idx = blockIdx.y * 72 + blockIdx.x;
        if (idx >= 1536) return;
        const int i = (idx * 256 + threadIdx.x) * 8;
        f32x4 a = *(const f32x4*)&x[i];
        f32x4 c = *(const f32x4*)&x[i + 4];
        u16x8 o;
#pragma unroll
        for (int j = 0; j < 4; ++j) {
            o[j]     = (unsigned short)f2bf(a[j]);
            o[4 + j] = (unsigned short)f2bf(c[j]);
        }
        *(u16x8*)&x_bf[i] = o;
        return;
    }
    if (z == 3) {
        if (blockIdx.y != 0) return;
        const int xk = blockIdx.x;
        if (xk < 3) {  // bias_text
            const int o = xk * 256 + threadIdx.x;
            float s = 0.f;
#pragma unroll
            for (int r = 0; r < 4; ++r)
                s += tw[((size_t)r * 769 + 768) * 768 + o] + tb[r * 768 + o];
            tbias[o] = s;
        } else if (xk < 51) {  // latf
            const int idx = xk - 3;
            const int b = idx & 1, ox = idx >> 1;
            const int o  = ox * 32 + (threadIdx.x >> 3);
            const int ip = threadIdx.x & 7;
            float s = 0.f;
            for (int i = ip; i < 769; i += 8) {
                float coef = (i < 768) ? lat[b * 768 + i] : 1.0f;
                float wsum = 0.f;
#pragma unroll
                for (int r = 0; r < 4; ++r) wsum += lw[((size_t)r * 769 + i) * 768 + o];
                s += coef * wsum;
            }
            s += __shfl_xor(s, 1);
            s += __shfl_xor(s, 2);
            s += __shfl_xor(s, 4);
            if (ip == 0) {
                float bb = 0.f;
#pragma unroll
                for (int r = 0; r < 4; ++r) bb += lb[r * 768 + o];
                latf[b * 768 + o] = s + bb;
            }
        }
        return;
    }
    // transposes
    __shared__ float t[32][33];
    const float* in; bf16* out; int C, G; size_t rstr;
    if (z == 0)      { in = aw; out = awT; C = 2304; G = 1; rstr = 0; }
    else if (z == 1) { in = pw; out = pwT; C = 768;  G = 1; rstr = 0; }
    else             { in = tw; out = twT; C = 768;  G = 4; rstr = 769ul * 768; }
    const int c0 = blockIdx.x * 32, r0 = blockIdx.y * 32;
    if (c0 >= C) return;
    const int tx = threadIdx.x & 31, ty = threadIdx.x >> 5;
#pragma unroll
    for (int i = 0; i < 32; i += 8) {
        float s = 0.f;
        for (int g = 0; g < G; ++g)
            s += in[g * rstr + (size_t)(r0 + ty + i) * C + c0 + tx];
        t[ty + i][tx] = s;
    }
    __syncthreads();
#pragma unroll
    for (int i = 0; i < 32; i += 8)
        out[(size_t)(c0 + ty + i) * 768 + r0 + tx] = __float2bfloat16(t[tx][ty + i]);
}

// V part of qkv (cols 1536..2303) -> vT[bh][d][s]  (bf16 raw u16 copy)
__global__ void vtrans_k(const unsigned short* __restrict__ qkv,
                         unsigned short* __restrict__ vT) {
    __shared__ unsigned short t[64][72];
    const int bh = blockIdx.y, b = bh / 12, h = bh - b * 12;
    const int s0 = blockIdx.x * 64;
    const int tr = threadIdx.x >> 3, tc = (threadIdx.x & 7) * 8;
#pragma unroll
    for (int p = 0; p < 2; ++p) {
        int sr = tr + p * 32;
        *(u16x8*)&t[sr][tc] =
            *(const u16x8*)&qkv[(size_t)(b * 2048 + s0 + sr) * 2304 + 1536 + h * 64 + tc];
    }
    __syncthreads();
#pragma unroll
    for (int p = 0; p < 2; ++p) {
        int d = tr + p * 32;
        u16x8 v;
#pragma unroll
        for (int j = 0; j < 8; ++j) v[j] = t[tc + j][d];
        *(u16x8*)&vT[((size_t)bh * 64 + d) * 2048 + s0 + tc] = v;
    }
}

// ---------------------------------------------------------------- GEMM (m97 structure)
// C[M,N] = A[M,K] @ Bt[N,K]^T ; 128xTN tile, BK=32, 4 waves, 16x16x32 bf16 MFMA.
// EPI 0: +bias -> bf16 (qkv)  EPI 1: (acc+bias)*latf*(0.125*log2e) -> bf16 (fused q)
// EPI 2: +bias -> f32 (final out)
template <int EPI, int TN>
__global__ __launch_bounds__(256) void gemm_bt(
    const bf16* __restrict__ A, int lda, const bf16* __restrict__ Bt,
    const float* __restrict__ bias, const float* __restrict__ latf,
    void* __restrict__ Cout, int ldc, int K) {
    constexpr int FN = TN / 32;
    __shared__ bf16 Al[128 * 32];
    __shared__ bf16 Bl[TN * 32];
    const int tid = threadIdx.x, w = tid >> 6, lane = tid & 63;
    const int row0 = blockIdx.x * 128, col0 = blockIdx.y * TN;
    const int wm = (w >> 1) * 64, wn = (w & 1) * (TN / 2);
    const int lr = lane & 15, lk8 = (lane >> 4) * 8, lq = lane >> 4;
    const int sr = lane >> 2;
    const int sc = (lane & 3) * 8;
    f32x4 acc[4][FN] = {};
    for (int k0 = 0; k0 < K; k0 += 32) {
#pragma unroll
        for (int i = 0; i < 2; ++i) {
            const int rr = w * 32 + i * 16;
            gload_lds16(A + (size_t)(row0 + rr + sr) * lda + k0 + sc, &Al[rr * 32]);
        }
#pragma unroll
        for (int i = 0; i < TN / 64; ++i) {
            const int rb = (w * (TN / 64) + i) * 16;
            gload_lds16(Bt + (size_t)(col0 + rb + sr) * K + k0 + sc, &Bl[rb * 32]);
        }
        __syncthreads();
        s16x8 af[4], bfr[FN];
#pragma unroll
        for (int m = 0; m < 4; ++m) af[m]  = *(const s16x8*)&Al[(wm + m * 16 + lr) * 32 + lk8];
#pragma unroll
        for (int n = 0; n < FN; ++n) bfr[n] = *(const s16x8*)&Bl[(wn + n * 16 + lr) * 32 + lk8];
        __builtin_amdgcn_s_setprio(1);
#pragma unroll
        for (int m = 0; m < 4; ++m)
#pragma unroll
            for (int n = 0; n < FN; ++n)
                acc[m][n] = __builtin_amdgcn_mfma_f32_16x16x32_bf16(af[m], bfr[n], acc[m][n], 0, 0, 0);
        __builtin_amdgcn_s_setprio(0);
        __syncthreads();
    }
#pragma unroll
    for (int m = 0; m < 4; ++m)
#pragma unroll
        for (int n = 0; n < FN; ++n)
#pragma unroll
            for (int r = 0; r < 4; ++r) {
                const int row = row0 + wm + m * 16 + lq * 4 + r;
                const int col = col0 + wn + n * 16 + lr;
                const float v = acc[m][n][r];
                if (EPI == 0) {
                    ((bf16*)Cout)[(size_t)row * ldc + col] = __float2bfloat16(v + bias[col]);
                } else if (EPI == 1) {
                    ((bf16*)Cout)[(size_t)row * ldc + col] = __float2bfloat16(
                        (v + bias[col]) * latf[(row >> 11) * 768 + col] * 0.18033688011112042f);
                } else {
                    ((float*)Cout)[(size_t)row * ldc + col] = v + bias[col];
                }
            }
}

// ---------------------------------------------------------------- flash attention
// 256 blocks x 12 waves = 3072 waves (3/SIMD). Pair task (p, 127-p) of one head
// (uniform 33 KV-tiles) split across 2 waves: side0 = light tile FULL + heavy
// keys [0,h0); side1 = heavy keys [h0,H). Flash-merge via LDS + one barrier.
// Swapped QK^T: S^T = mfma(K,Q) => lane owns q-row (q=lane&15): row-max = in-lane
// max + 2 shfl; P-transpose = 4x ds_write_b64 + 2x ds_read_b128 (bf16);
// PV: O^T = mfma(V^T, P) puts q back in lane&15 (no shuffles for norm/output).
// Softmax in exp2 domain (log2e folded into qf prescale).
__global__ __launch_bounds__(768, 3) void attn_k(
    const bf16* __restrict__ qf, const bf16* __restrict__ qkv,
    const bf16* __restrict__ vT, bf16* __restrict__ aout) {
    __shared__ unsigned short Pl[12][16][72];
    __shared__ float comb[6][64][18];
    const int w = threadIdx.x >> 6, lane = threadIdx.x & 63;
    const int lb = (blockIdx.x & 7) * 32 + (blockIdx.x >> 3);  // XCD swizzle: 3 heads/XCD
    const int j = w >> 1, side = w & 1;
    const int g = lb * 6 + j;                  // pair id 0..1535
    const int bh = g >> 6, pr = g & 63;
    const int b = bh / 12, h = bh - b * 12;
    const int lr = lane & 15, lq = lane >> 4, lk8 = lq * 8;
    unsigned short (*Pw)[72] = Pl[w];
    const bf16* Kp = qkv + (size_t)b * 2048 * 2304 + 768 + h * 64 + (size_t)lr * 2304 + lk8;
    const bf16* Vp = vT + (size_t)bh * 64 * 2048 + (size_t)lr * 2048 + lk8;
    const int L  = (16 * pr + 79) >> 6;        // light-tile KV count
    const int H  = (2111 - 16 * pr) >> 6;      // heavy-tile KV count (L+H == 33)
    const int h0 = 17 - L;                     // heavy split point

#define LOADK(T, DST)                                                                    \
    do {                                                                                 \
        const size_t kb0_ = (size_t)(T) * 64 * 2304;                                     \
        _Pragma("unroll") for (int ks_ = 0; ks_ < 2; ++ks_)                              \
            _Pragma("unroll") for (int n_ = 0; n_ < 4; ++n_)                             \
                DST[ks_][n_] = *(const s16x8*)&Kp[kb0_ + (size_t)n_ * 16 * 2304 +        \
                                                 ks_ * 32];                              \
    } while (0)

#define ABODY(kc, kn)                                                                    \
    do {                                                                                 \
        const int kv0_ = t * 64;                                                         \
        s16x8 vb_[2][4];                                                                 \
        _Pragma("unroll") for (int ks_ = 0; ks_ < 2; ++ks_)                              \
            _Pragma("unroll") for (int dn_ = 0; dn_ < 4; ++dn_)                          \
                vb_[ks_][dn_] = *(const s16x8*)&Vp[(size_t)dn_ * 32768 + kv0_ +          \
                                                   ks_ * 32];                            \
        f32x4 st_[4] = {};                                                               \
        __builtin_amdgcn_s_setprio(1);                                                   \
        _Pragma("unroll") for (int ks_ = 0; ks_ < 2; ++ks_)                              \
            _Pragma("unroll") for (int n_ = 0; n_ < 4; ++n_)                             \
                st_[n_] = __builtin_amdgcn_mfma_f32_16x16x32_bf16(kc[ks_][n_], qa[ks_],  \
                                                                  st_[n_], 0, 0, 0);     \
        __builtin_amdgcn_s_setprio(0);                                                   \
        if (t + 1 < t1) LOADK(t + 1, kn);                                                \
        if (maskLast && t == t1 - 1) {                                                   \
            _Pragma("unroll") for (int n_ = 0; n_ < 4; ++n_)                             \
                _Pragma("unroll") for (int r_ = 0; r_ < 4; ++r_)                         \
                    if (kv0_ + n_ * 16 + lq * 4 + r_ > qpos + lr) st_[n_][r_] = -10000.f;\
        }                                                                                \
        f32x4 m4_ = vmax4(vmax4(st_[0], st_[1]), vmax4(st_[2], st_[3]));                 \
        float v_ = fmaxf(fmaxf(m4_[0], m4_[1]), fmaxf(m4_[2], m4_[3]));                  \
        v_ = fmaxf(v_, __shfl_xor(v_, 16));                                              \
        v_ = fmaxf(v_, __shfl_xor(v_, 32));                                              \
        const float newm_ = fmaxf(mr, v_);                                               \
        const float scl_ = __builtin_amdgcn_exp2f(mr - newm_);                           \
        mr = newm_;                                                                      \
        _Pragma("unroll") for (int n_ = 0; n_ < 4; ++n_)                                 \
            _Pragma("unroll") for (int e_ = 0; e_ < 4; ++e_)                             \
                st_[n_][e_] = __builtin_amdgcn_exp2f(st_[n_][e_] - newm_);               \
        f32x4 ps4_ = (st_[0] + st_[1]) + (st_[2] + st_[3]);                              \
        lsum = lsum * scl_ + ((ps4_[0] + ps4_[1]) + (ps4_[2] + ps4_[3]));                \
        _Pragma("unroll") for (int dn_ = 0; dn_ < 4; ++dn_) oacc[dn_] *= scl_;           \
        _Pragma("unroll") for (int n_ = 0; n_ < 4; ++n_) {                               \
            s16x4 pk_;                                                                   \
            _Pragma("unroll") for (int r_ = 0; r_ < 4; ++r_) pk_[r_] = f2bf(st_[n_][r_]);\
            *(s16x4*)&Pw[lr][n_ * 16 + lq * 4] = pk_;                                    \
        }                                                                                \
        s16x8 pb_[2];                                                                    \
        _Pragma("unroll") for (int ks_ = 0; ks_ < 2; ++ks_)                              \
            pb_[ks_] = *(const s16x8*)&Pw[lr][ks_ * 32 + lk8];                           \
        __builtin_amdgcn_s_setprio(1);                                                   \
        _Pragma("unroll") for (int ks_ = 0; ks_ < 2; ++ks_)                              \
            _Pragma("unroll") for (int dn_ = 0; dn_ < 4; ++dn_)                          \
                oacc[dn_] = __builtin_amdgcn_mfma_f32_16x16x32_bf16(vb_[ks_][dn_],       \
                                                                    pb_[ks_], oacc[dn_], \
                                                                    0, 0, 0);            \
        __builtin_amdgcn_s_setprio(0);                                                   \
    } while (0)

    auto runRange = [&](int qpos, int t0, int t1, bool maskLast,
                        float& mr, float& lsum, f32x4 (&oacc)[4]) {
        s16x8 qa[2];
        const bf16* qp = qf + ((size_t)b * 2048 + qpos + lr) * 768 + h * 64 + lk8;
        qa[0] = *(const s16x8*)qp;
        qa[1] = *(const s16x8*)(qp + 32);
        s16x8 kA[2][4], kB[2][4];
        int t = t0;
        LOADK(t0, kA);
        while (true) {
            ABODY(kA, kB);
            if (++t == t1) break;
            ABODY(kB, kA);
            if (++t == t1) break;
        }
        lsum += __shfl_xor(lsum, 16);  // full row-sum across the 4 lane-groups
        lsum += __shfl_xor(lsum, 32);
    };

    float mr = -3.0e38f, lsum = 0.f;
    f32x4 oacc[4] = {};
    if (side == 0) {
        // light tile, complete
        runRange(16 * pr, 0, L, true, mr, lsum, oacc);
        const float inv = 1.0f / lsum;
        const size_t orow = ((size_t)b * 2048 + 16 * pr + lr) * 768 + h * 64 + lq * 4;
#pragma unroll
        for (int dn = 0; dn < 4; ++dn) {
            s16x4 o4;
#pragma unroll
            for (int r = 0; r < 4; ++r) o4[r] = f2bf(oacc[dn][r] * inv);
            *(s16x4*)&aout[orow + dn * 16] = o4;
        }
        // heavy tile, keys [0, h0)
        mr = -3.0e38f; lsum = 0.f;
#pragma unroll
        for (int dn = 0; dn < 4; ++dn) oacc[dn] = f32x4{};
        runRange(16 * (127 - pr), 0, h0, false, mr, lsum, oacc);
    } else {
        // heavy tile, keys [h0, H) (includes diagonal tile)
        runRange(16 * (127 - pr), h0, H, true, mr, lsum, oacc);
        float* cj = &comb[j][lane][0];
#pragma unroll
        for (int dn = 0; dn < 4; ++dn)
#pragma unroll
            for (int r = 0; r < 4; ++r) cj[dn * 4 + r] = oacc[dn][r];
        cj[16] = mr;
        cj[17] = lsum;
    }
    __syncthreads();
    if (side == 0) {  // flash-merge the heavy tile and write it
        const float* cj = &comb[j][lane][0];
        const float mC = cj[16], lC = cj[17];
        const float m  = fmaxf(mr, mC);
        const float f0 = __builtin_amdgcn_exp2f(mr - m);
        const float f1 = __builtin_amdgcn_exp2f(mC - m);
        const float linv = 1.0f / (lsum * f0 + lC * f1);
        const size_t orow =
            ((size_t)b * 2048 + 16 * (127 - pr) + lr) * 768 + h * 64 + lq * 4;
#pragma unroll
        for (int dn = 0; dn < 4; ++dn) {
            s16x4 o4;
#pragma unroll
            for (int r = 0; r < 4; ++r)
                o4[r] = f2bf((oacc[dn][r] * f0 + cj[dn * 4 + r] * f1) * linv);
            *(s16x4*)&aout[orow + dn * 16] = o4;
        }
    }
#undef ABODY
#undef LOADK
}

// ---------------------------------------------------------------- launch

extern "C" void kernel_launch(void* const* d_in, const int* in_sizes, int n_in,
                              void* d_out, int out_size, void* d_ws, size_t ws_size,
                              hipStream_t stream) {
    (void)in_sizes; (void)n_in; (void)out_size; (void)ws_size;
    const float* x      = (const float*)d_in[0];
    const float* lat    = (const float*)d_in[1];
    const float* attn_w = (const float*)d_in[2];
    const float* attn_b = (const float*)d_in[3];
    const float* proj_w = (const float*)d_in[4];
    const float* proj_b = (const float*)d_in[5];
    const float* text_w = (const float*)d_in[6];
    const float* text_b = (const float*)d_in[7];
    const float* lat_w  = (const float*)d_in[8];
    const float* lat_b  = (const float*)d_in[9];
    float* out = (float*)d_out;

    char* ws = (char*)d_ws;
    size_t off = 0;
    auto take = [&](size_t bytes) -> char* {
        char* p = ws + off;
        off = (off + bytes + 255) & ~(size_t)255;
        return p;
    };
    bf16* x_bf   = (bf16*)take(4096ul * 768 * 2);
    bf16* awT    = (bf16*)take(2304ul * 768 * 2);
    bf16* pwT    = (bf16*)take(768ul * 768 * 2);
    bf16* twT    = (bf16*)take(768ul * 768 * 2);
    bf16* qkv_bf = (bf16*)take(4096ul * 2304 * 2);
    bf16* qf_bf  = (bf16*)take(4096ul * 768 * 2);
    bf16* vT     = (bf16*)take(24ul * 64 * 2048 * 2);
    bf16* a_bf   = (bf16*)take(4096ul * 768 * 2);
    float* tbias = (float*)take(768 * 4);
    float* latf  = (float*)take(2 * 768 * 4);

    prep_all<<<dim3(72, 24, 5), 256, 0, stream>>>(x, attn_w, proj_w, text_w, text_b,
                                                  lat, lat_w, lat_b, x_bf, awT, pwT,
                                                  twT, tbias, latf);
    gemm_bt<0, 128><<<dim3(32, 18), 256, 0, stream>>>(x_bf, 768, awT, attn_b, nullptr,
                                                      qkv_bf, 2304, 768);
    vtrans_k<<<dim3(32, 24), 256, 0, stream>>>((const unsigned short*)qkv_bf,
                                               (unsigned short*)vT);
    gemm_bt<1, 64><<<dim3(32, 12), 256, 0, stream>>>(qkv_bf, 2304, twT, tbias, latf,
                                                     qf_bf, 768, 768);
    attn_k<<<256, 768, 0, stream>>>(qf_bf, qkv_bf, vT, a_bf);
    gemm_bt<2, 64><<<dim3(32, 12), 256, 0, stream>>>(a_bf, 768, pwT, proj_b, nullptr,
                                                     out, 768, 768);
}

// Round 8
// 236.687 us; speedup vs baseline: 1.4269x; 1.2436x over previous
//
#include <hip/hip_runtime.h>
#include <hip/hip_bf16.h>
#include <cstdint>

#define DEV __device__ __forceinline__

typedef short  s16x8 __attribute__((ext_vector_type(8)));
typedef short  s16x4 __attribute__((ext_vector_type(4)));
typedef unsigned short u16x8 __attribute__((ext_vector_type(8)));
typedef float  f32x4 __attribute__((ext_vector_type(4)));
typedef __hip_bfloat16 bf16;

DEV short f2bf(float f) {
    __hip_bfloat16 h = __float2bfloat16(f);
    return __builtin_bit_cast(short, h);
}

DEV f32x4 vmax4(f32x4 a, f32x4 b) {
    f32x4 r;
#pragma unroll
    for (int j = 0; j < 4; ++j) r[j] = fmaxf(a[j], b[j]);
    return r;
}

// global -> LDS async copy, 16B per lane; LDS base must be wave-uniform.
DEV void gload_lds16(const void* g, void* l) {
    __builtin_amdgcn_global_load_lds(
        (const __attribute__((address_space(1))) uint32_t*)g,
        (__attribute__((address_space(3))) uint32_t*)l, 16, 0, 0);
}

// ---------------------------------------------------------------- prep (one launch)
// z=0: attn_w^T (768x2304->T)  z=1: proj_w^T  z=2: sum_r text_w^T
// z=3: bias_text (x<3) + latf (3<=x<51)   z=4: x fp32->bf16
__global__ void prep_all(const float* __restrict__ x, const float* __restrict__ aw,
                         const float* __restrict__ pw, const float* __restrict__ tw,
                         const float* __restrict__ tb, const float* __restrict__ lat,
                         const float* __restrict__ lw, const float* __restrict__ lb,
                         bf16* __restrict__ x_bf, bf16* __restrict__ awT,
                         bf16* __restrict__ pwT, bf16* __restrict__ twT,
                         float* __restrict__ tbias, float* __restrict__ latf) {
    const int z = blockIdx.z;
    if (z == 4) {  // convert x
        const int idx = blockIdx.y * 72 + blockIdx.x;
        if (idx >= 1536) return;
        const int i = (idx * 256 + threadIdx.x) * 8;
        f32x4 a = *(const f32x4*)&x[i];
        f32x4 c = *(const f32x4*)&x[i + 4];
        u16x8 o;
#pragma unroll
        for (int j = 0; j < 4; ++j) {
            o[j]     = (unsigned short)f2bf(a[j]);
            o[4 + j] = (unsigned short)f2bf(c[j]);
        }
        *(u16x8*)&x_bf[i] = o;
        return;
    }
    if (z == 3) {
        if (blockIdx.y != 0) return;
        const int xk = blockIdx.x;
        if (xk < 3) {  // bias_text
            const int o = xk * 256 + threadIdx.x;
            float s = 0.f;
#pragma unroll
            for (int r = 0; r < 4; ++r)
                s += tw[((size_t)r * 769 + 768) * 768 + o] + tb[r * 768 + o];
            tbias[o] = s;
        } else if (xk < 51) {  // latf
            const int idx = xk - 3;
            const int b = idx & 1, ox = idx >> 1;
            const int o  = ox * 32 + (threadIdx.x >> 3);
            const int ip = threadIdx.x & 7;
            float s = 0.f;
            for (int i = ip; i < 769; i += 8) {
                float coef = (i < 768) ? lat[b * 768 + i] : 1.0f;
                float wsum = 0.f;
#pragma unroll
                for (int r = 0; r < 4; ++r) wsum += lw[((size_t)r * 769 + i) * 768 + o];
                s += coef * wsum;
            }
            s += __shfl_xor(s, 1);
            s += __shfl_xor(s, 2);
            s += __shfl_xor(s, 4);
            if (ip == 0) {
                float bb = 0.f;
#pragma unroll
                for (int r = 0; r < 4; ++r) bb += lb[r * 768 + o];
                latf[b * 768 + o] = s + bb;
            }
        }
        return;
    }
    // transposes
    __shared__ float t[32][33];
    const float* in; bf16* out; int C, G; size_t rstr;
    if (z == 0)      { in = aw; out = awT; C = 2304; G = 1; rstr = 0; }
    else if (z == 1) { in = pw; out = pwT; C = 768;  G = 1; rstr = 0; }
    else             { in = tw; out = twT; C = 768;  G = 4; rstr = 769ul * 768; }
    const int c0 = blockIdx.x * 32, r0 = blockIdx.y * 32;
    if (c0 >= C) return;
    const int tx = threadIdx.x & 31, ty = threadIdx.x >> 5;
#pragma unroll
    for (int i = 0; i < 32; i += 8) {
        float s = 0.f;
        for (int g = 0; g < G; ++g)
            s += in[g * rstr + (size_t)(r0 + ty + i) * C + c0 + tx];
        t[ty + i][tx] = s;
    }
    __syncthreads();
#pragma unroll
    for (int i = 0; i < 32; i += 8)
        out[(size_t)(c0 + ty + i) * 768 + r0 + tx] = __float2bfloat16(t[tx][ty + i]);
}

// ---------------------------------------------------------------- GEMM (m97 structure)
// C[M,N] = A[M,K] @ Bt[N,K]^T ; 128xTN tile, BK=32, 4 waves, 16x16x32 bf16 MFMA.
// EPI 0: +bias -> bf16 qkv for cols<1536; V-cols (>=1536) go ONLY to vT[bh][d][s].
// EPI 1: (acc+bias)*latf*(0.125*log2e) -> bf16 (fused q)   EPI 2: +bias -> f32
template <int EPI, int TN>
__global__ __launch_bounds__(256) void gemm_bt(
    const bf16* __restrict__ A, int lda, const bf16* __restrict__ Bt,
    const float* __restrict__ bias, const float* __restrict__ latf,
    void* __restrict__ Cout, bf16* __restrict__ vTout, int ldc, int K) {
    constexpr int FN = TN / 32;
    __shared__ bf16 Al[128 * 32];
    __shared__ bf16 Bl[TN * 32];
    const int tid = threadIdx.x, w = tid >> 6, lane = tid & 63;
    const int row0 = blockIdx.x * 128, col0 = blockIdx.y * TN;
    const int wm = (w >> 1) * 64, wn = (w & 1) * (TN / 2);
    const int lr = lane & 15, lk8 = (lane >> 4) * 8, lq = lane >> 4;
    const int sr = lane >> 2;
    const int sc = (lane & 3) * 8;
    f32x4 acc[4][FN] = {};
    for (int k0 = 0; k0 < K; k0 += 32) {
#pragma unroll
        for (int i = 0; i < 2; ++i) {
            const int rr = w * 32 + i * 16;
            gload_lds16(A + (size_t)(row0 + rr + sr) * lda + k0 + sc, &Al[rr * 32]);
        }
#pragma unroll
        for (int i = 0; i < TN / 64; ++i) {
            const int rb = (w * (TN / 64) + i) * 16;
            gload_lds16(Bt + (size_t)(col0 + rb + sr) * K + k0 + sc, &Bl[rb * 32]);
        }
        __syncthreads();
        s16x8 af[4], bfr[FN];
#pragma unroll
        for (int m = 0; m < 4; ++m) af[m]  = *(const s16x8*)&Al[(wm + m * 16 + lr) * 32 + lk8];
#pragma unroll
        for (int n = 0; n < FN; ++n) bfr[n] = *(const s16x8*)&Bl[(wn + n * 16 + lr) * 32 + lk8];
        __builtin_amdgcn_s_setprio(1);
#pragma unroll
        for (int m = 0; m < 4; ++m)
#pragma unroll
            for (int n = 0; n < FN; ++n)
                acc[m][n] = __builtin_amdgcn_mfma_f32_16x16x32_bf16(af[m], bfr[n], acc[m][n], 0, 0, 0);
        __builtin_amdgcn_s_setprio(0);
        __syncthreads();
    }
#pragma unroll
    for (int m = 0; m < 4; ++m)
#pragma unroll
        for (int n = 0; n < FN; ++n) {
            const int rowb = row0 + wm + m * 16 + lq * 4;  // r spans rowb..rowb+3
            const int col  = col0 + wn + n * 16 + lr;
            if (EPI == 0 && col0 >= 1536) {
                // V region: write only vT[bh][d][s] (packed over r = consecutive s)
                const int vcol = col - 1536;
                s16x4 vo;
#pragma unroll
                for (int r = 0; r < 4; ++r) vo[r] = f2bf(acc[m][n][r] + bias[col]);
                bf16* vdst = vTout +
                    ((size_t)((rowb >> 11) * 12 + (vcol >> 6)) * 64 + (vcol & 63)) * 2048 +
                    (rowb & 2047);
                *(s16x4*)vdst = vo;
            } else {
#pragma unroll
                for (int r = 0; r < 4; ++r) {
                    const int row = rowb + r;
                    const float v = acc[m][n][r];
                    if (EPI == 0) {
                        ((bf16*)Cout)[(size_t)row * ldc + col] = __float2bfloat16(v + bias[col]);
                    } else if (EPI == 1) {
                        ((bf16*)Cout)[(size_t)row * ldc + col] = __float2bfloat16(
                            (v + bias[col]) * latf[(row >> 11) * 768 + col] * 0.18033688011112042f);
                    } else {
                        ((float*)Cout)[(size_t)row * ldc + col] = v + bias[col];
                    }
                }
            }
        }
}

// ---------------------------------------------------------------- flash attention
// 192 blocks (24 bh x 8 pairs, XCD-grouped: 3 heads per XCD) x 8 waves (512 thr).
// Block runs TWO q-tiles sequentially: light [128p,128p+128) over L=2p+2 KV tiles,
// heavy [2048-128(p+1), ..+128) over H=32-2p tiles => uniform 34 stage-iters/block.
// Each wave owns 16 q-rows/phase. K (64x64) and V^T (64x64) LDS-staged per tile via
// global_load_lds, double-buffered, XOR-swizzled (linear LDS dest + pre-swizzled
// per-lane global src, swizzled ds_read — rule #21). One __syncthreads per tile
// (its vmcnt(0)+lgkmcnt(0) drain is exactly the needed fence). Swapped QK^T:
// lane owns q-row (lr); softmax = in-lane max + 2 shfl; P via per-wave LDS;
// PV: O^T = mfma(V^T, P^T). exp2 domain (log2e*0.125 folded into qf).
__global__ __launch_bounds__(512, 2) void attn_k(
    const bf16* __restrict__ qf, const bf16* __restrict__ qkv,
    const bf16* __restrict__ vT, bf16* __restrict__ aout) {
    __shared__ bf16 KL[2][4096];
    __shared__ bf16 VL[2][4096];
    __shared__ unsigned short Pl[8][16][68];
    const int w = threadIdx.x >> 6, lane = threadIdx.x & 63;
    // 192 blocks: xcd = blk&7 gets 3 heads; p = pair index
    const int bh = (blockIdx.x & 7) * 3 + (blockIdx.x >> 3) / 8;
    const int p  = (blockIdx.x >> 3) & 7;
    const int b = bh / 12, h = bh - b * 12;
    const int lr = lane & 15, lq = lane >> 4;
    // staging lane mapping: row = 8w + (lane>>3), chunk = (lane&7) ^ ((lane>>3)&7)
    const int sw_row = 8 * w + (lane >> 3);
    const int sw_ck  = (lane & 7) ^ ((lane >> 3) & 7);
    const bf16* Kg = qkv + (size_t)b * 2048 * 2304 + 768 + h * 64;  // rows = keys
    const bf16* Vg = vT + (size_t)bh * 64 * 2048;                   // rows = d

    auto STAGE = [&](int t, int buf) {
        const int kv0s = t * 64;
        gload_lds16(Kg + (size_t)(kv0s + sw_row) * 2304 + sw_ck * 8, &KL[buf][w * 512]);
        gload_lds16(Vg + (size_t)sw_row * 2048 + kv0s + sw_ck * 8, &VL[buf][w * 512]);
    };

#pragma unroll 1
    for (int ph = 0; ph < 2; ++ph) {
        const int qpos0 = ph ? 2048 - 128 * (p + 1) : 128 * p;
        const int T     = ph ? 32 - 2 * p : 2 * p + 2;
        const int qw    = qpos0 + 16 * w;        // wave's first q-row (seq pos)
        const size_t grow = (size_t)b * 2048 + qw;
        s16x8 qa0, qa1;
        {
            const bf16* qp = qf + (grow + lr) * 768 + h * 64 + lq * 8;
            qa0 = *(const s16x8*)qp;
            qa1 = *(const s16x8*)(qp + 32);
        }
        float mr = -3.0e38f, lsum = 0.f;
        f32x4 oacc[4] = {};
        int myT = (qw + 79) >> 6;
        if (myT > T) myT = T;
        STAGE(0, 0);
        __syncthreads();
        for (int t = 0; t < T; ++t) {
            const int cur = t & 1;
            if (t + 1 < T) STAGE(t + 1, cur ^ 1);
            if (t < myT) {
                const int kv0 = t * 64;
                f32x4 st[4] = {};
                __builtin_amdgcn_s_setprio(1);
#pragma unroll
                for (int ks = 0; ks < 2; ++ks) {
                    const int ck = ((4 * ks + lq) ^ (lr & 7)) * 8;
                    const s16x8 qa = ks ? qa1 : qa0;
#pragma unroll
                    for (int n = 0; n < 4; ++n) {
                        s16x8 kb = *(const s16x8*)&KL[cur][(n * 16 + lr) * 64 + ck];
                        st[n] = __builtin_amdgcn_mfma_f32_16x16x32_bf16(kb, qa, st[n], 0, 0, 0);
                    }
                }
                __builtin_amdgcn_s_setprio(0);
                if (kv0 + 63 > qw) {  // diagonal tile(s): causal mask
#pragma unroll
                    for (int n = 0; n < 4; ++n)
#pragma unroll
                        for (int r = 0; r < 4; ++r)
                            if (kv0 + n * 16 + lq * 4 + r > qw + lr) st[n][r] = -10000.f;
                }
                // online softmax (exp2 domain); lane owns row q=lr
                f32x4 m4 = vmax4(vmax4(st[0], st[1]), vmax4(st[2], st[3]));
                float v = fmaxf(fmaxf(m4[0], m4[1]), fmaxf(m4[2], m4[3]));
                v = fmaxf(v, __shfl_xor(v, 16));
                v = fmaxf(v, __shfl_xor(v, 32));
                const float newm = fmaxf(mr, v);
                const float scl = __builtin_amdgcn_exp2f(mr - newm);
                mr = newm;
#pragma unroll
                for (int n = 0; n < 4; ++n)
#pragma unroll
                    for (int e = 0; e < 4; ++e)
                        st[n][e] = __builtin_amdgcn_exp2f(st[n][e] - newm);
                f32x4 ps4 = (st[0] + st[1]) + (st[2] + st[3]);
                lsum = lsum * scl + ((ps4[0] + ps4[1]) + (ps4[2] + ps4[3]));
#pragma unroll
                for (int dn = 0; dn < 4; ++dn) oacc[dn] *= scl;
                // P -> per-wave LDS (transpose to B-fragment layout)
#pragma unroll
                for (int n = 0; n < 4; ++n) {
                    s16x4 pk;
#pragma unroll
                    for (int r = 0; r < 4; ++r) pk[r] = f2bf(st[n][r]);
                    *(s16x4*)&Pl[w][lr][n * 16 + lq * 4] = pk;
                }
                __builtin_amdgcn_s_setprio(1);
#pragma unroll
                for (int ks = 0; ks < 2; ++ks) {
                    const s16x8 pb = *(const s16x8*)&Pl[w][lr][ks * 32 + lq * 8];
                    const int ck = ((4 * ks + lq) ^ (lr & 7)) * 8;
#pragma unroll
                    for (int dn = 0; dn < 4; ++dn) {
                        s16x8 vb = *(const s16x8*)&VL[cur][(dn * 16 + lr) * 64 + ck];
                        oacc[dn] = __builtin_amdgcn_mfma_f32_16x16x32_bf16(vb, pb, oacc[dn], 0, 0, 0);
                    }
                }
                __builtin_amdgcn_s_setprio(0);
            }
            __syncthreads();
        }
        lsum += __shfl_xor(lsum, 16);
        lsum += __shfl_xor(lsum, 32);
        const float inv = 1.0f / lsum;
#pragma unroll
        for (int dn = 0; dn < 4; ++dn) {
            s16x4 o4;
#pragma unroll
            for (int r = 0; r < 4; ++r) o4[r] = f2bf(oacc[dn][r] * inv);
            *(s16x4*)&aout[(grow + lr) * 768 + h * 64 + dn * 16 + lq * 4] = o4;
        }
    }
}

// ---------------------------------------------------------------- launch

extern "C" void kernel_launch(void* const* d_in, const int* in_sizes, int n_in,
                              void* d_out, int out_size, void* d_ws, size_t ws_size,
                              hipStream_t stream) {
    (void)in_sizes; (void)n_in; (void)out_size; (void)ws_size;
    const float* x      = (const float*)d_in[0];
    const float* lat    = (const float*)d_in[1];
    const float* attn_w = (const float*)d_in[2];
    const float* attn_b = (const float*)d_in[3];
    const float* proj_w = (const float*)d_in[4];
    const float* proj_b = (const float*)d_in[5];
    const float* text_w = (const float*)d_in[6];
    const float* text_b = (const float*)d_in[7];
    const float* lat_w  = (const float*)d_in[8];
    const float* lat_b  = (const float*)d_in[9];
    float* out = (float*)d_out;

    char* ws = (char*)d_ws;
    size_t off = 0;
    auto take = [&](size_t bytes) -> char* {
        char* p = ws + off;
        off = (off + bytes + 255) & ~(size_t)255;
        return p;
    };
    bf16* x_bf   = (bf16*)take(4096ul * 768 * 2);
    bf16* awT    = (bf16*)take(2304ul * 768 * 2);
    bf16* pwT    = (bf16*)take(768ul * 768 * 2);
    bf16* twT    = (bf16*)take(768ul * 768 * 2);
    bf16* qkv_bf = (bf16*)take(4096ul * 2304 * 2);
    bf16* qf_bf  = (bf16*)take(4096ul * 768 * 2);
    bf16* vT     = (bf16*)take(24ul * 64 * 2048 * 2);
    bf16* a_bf   = (bf16*)take(4096ul * 768 * 2);
    float* tbias = (float*)take(768 * 4);
    float* latf  = (float*)take(2 * 768 * 4);

    prep_all<<<dim3(72, 24, 5), 256, 0, stream>>>(x, attn_w, proj_w, text_w, text_b,
                                                  lat, lat_w, lat_b, x_bf, awT, pwT,
                                                  twT, tbias, latf);
    gemm_bt<0, 128><<<dim3(32, 18), 256, 0, stream>>>(x_bf, 768, awT, attn_b, nullptr,
                                                      qkv_bf, vT, 2304, 768);
    gemm_bt<1, 64><<<dim3(32, 12), 256, 0, stream>>>(qkv_bf, 2304, twT, tbias, latf,
                                                     qf_bf, nullptr, 768, 768);
    attn_k<<<192, 512, 0, stream>>>(qf_bf, qkv_bf, vT, a_bf);
    gemm_bt<2, 64><<<dim3(32, 12), 256, 0, stream>>>(a_bf, 768, pwT, proj_b, nullptr,
                                                     out, nullptr, 768, 768);
}

// Round 9
// 208.207 us; speedup vs baseline: 1.6221x; 1.1368x over previous
//
#include <hip/hip_runtime.h>
#include <hip/hip_bf16.h>
#include <cstdint>

#define DEV __device__ __forceinline__

typedef short  s16x8 __attribute__((ext_vector_type(8)));
typedef short  s16x4 __attribute__((ext_vector_type(4)));
typedef unsigned short u16x8 __attribute__((ext_vector_type(8)));
typedef float  f32x4 __attribute__((ext_vector_type(4)));
typedef __hip_bfloat16 bf16;

DEV short f2bf(float f) {
    __hip_bfloat16 h = __float2bfloat16(f);
    return __builtin_bit_cast(short, h);
}

DEV f32x4 vmax4(f32x4 a, f32x4 b) {
    f32x4 r;
#pragma unroll
    for (int j = 0; j < 4; ++j) r[j] = fmaxf(a[j], b[j]);
    return r;
}

// global -> LDS async copy, 16B per lane; LDS base must be wave-uniform.
DEV void gload_lds16(const void* g, void* l) {
    __builtin_amdgcn_global_load_lds(
        (const __attribute__((address_space(1))) uint32_t*)g,
        (__attribute__((address_space(3))) uint32_t*)l, 16, 0, 0);
}

// ---------------------------------------------------------------- prep (one launch)
// z=0: attn_w^T (768x2304->T)  z=1: proj_w^T  z=2: sum_r text_w^T
// z=3: bias_text (x<3) + latf INIT (3<=x<9: bias+ones-row terms)  z=4: x fp32->bf16
__global__ void prep_all(const float* __restrict__ x, const float* __restrict__ aw,
                         const float* __restrict__ pw, const float* __restrict__ tw,
                         const float* __restrict__ tb, const float* __restrict__ lat,
                         const float* __restrict__ lw, const float* __restrict__ lb,
                         bf16* __restrict__ x_bf, bf16* __restrict__ awT,
                         bf16* __restrict__ pwT, bf16* __restrict__ twT,
                         float* __restrict__ tbias, float* __restrict__ latf) {
    const int z = blockIdx.z;
    if (z == 4) {  // convert x
        const int idx = blockIdx.y * 72 + blockIdx.x;
        if (idx >= 1536) return;
        const int i = (idx * 256 + threadIdx.x) * 8;
        f32x4 a = *(const f32x4*)&x[i];
        f32x4 c = *(const f32x4*)&x[i + 4];
        u16x8 o;
#pragma unroll
        for (int j = 0; j < 4; ++j) {
            o[j]     = (unsigned short)f2bf(a[j]);
            o[4 + j] = (unsigned short)f2bf(c[j]);
        }
        *(u16x8*)&x_bf[i] = o;
        return;
    }
    if (z == 3) {
        if (blockIdx.y != 0) return;
        const int xk = blockIdx.x;
        if (xk < 3) {  // bias_text
            const int o = xk * 256 + threadIdx.x;
            float s = 0.f;
#pragma unroll
            for (int r = 0; r < 4; ++r)
                s += tw[((size_t)r * 769 + 768) * 768 + o] + tb[r * 768 + o];
            tbias[o] = s;
        } else if (xk < 9) {  // latf init: ones-row of lat_w + summed bias
            const int idx = (xk - 3) * 256 + threadIdx.x;  // 0..1535
            const int bb = idx >= 768 ? 1 : 0;
            const int o = idx - bb * 768;
            float s = 0.f;
#pragma unroll
            for (int r = 0; r < 4; ++r)
                s += lw[((size_t)r * 769 + 768) * 768 + o] + lb[r * 768 + o];
            latf[bb * 768 + o] = s;
        }
        return;
    }
    // transposes
    __shared__ float t[32][33];
    const float* in; bf16* out; int C, G; size_t rstr;
    if (z == 0)      { in = aw; out = awT; C = 2304; G = 1; rstr = 0; }
    else if (z == 1) { in = pw; out = pwT; C = 768;  G = 1; rstr = 0; }
    else             { in = tw; out = twT; C = 768;  G = 4; rstr = 769ul * 768; }
    const int c0 = blockIdx.x * 32, r0 = blockIdx.y * 32;
    if (c0 >= C) return;
    const int tx = threadIdx.x & 31, ty = threadIdx.x >> 5;
#pragma unroll
    for (int i = 0; i < 32; i += 8) {
        float s = 0.f;
        for (int g = 0; g < G; ++g)
            s += in[g * rstr + (size_t)(r0 + ty + i) * C + c0 + tx];
        t[ty + i][tx] = s;
    }
    __syncthreads();
#pragma unroll
    for (int i = 0; i < 32; i += 8)
        out[(size_t)(c0 + ty + i) * 768 + r0 + tx] = __float2bfloat16(t[tx][ty + i]);
}

// latf accumulation: latf[b][o] += sum_{i<768} lat[b][i] * sum_r lat_w[r][i][o].
// grid (12 o-chunks of 64, 8 i-chunks of 96); o coalesced across lanes; lw read
// once per block, used for both b; LDS partial-reduce, 1 atomicAdd per (b,o).
__global__ __launch_bounds__(256) void latf_partial(
    const float* __restrict__ lat, const float* __restrict__ lw,
    float* __restrict__ latf) {
    const int oc = blockIdx.x, ic = blockIdx.y;
    const int ol = threadIdx.x & 63, wv = threadIdx.x >> 6;
    const int o = oc * 64 + ol;
    float s0 = 0.f, s1 = 0.f;
#pragma unroll 4
    for (int t = 0; t < 24; ++t) {
        const int i = ic * 96 + wv * 24 + t;
        float wsum = 0.f;
#pragma unroll
        for (int r = 0; r < 4; ++r) wsum += lw[((size_t)r * 769 + i) * 768 + o];
        s0 += lat[i] * wsum;
        s1 += lat[768 + i] * wsum;
    }
    __shared__ float ps[2][4][64];
    ps[0][wv][ol] = s0;
    ps[1][wv][ol] = s1;
    __syncthreads();
    if (threadIdx.x < 128) {
        const int bb = threadIdx.x >> 6;
        float v = ps[bb][0][ol] + ps[bb][1][ol] + ps[bb][2][ol] + ps[bb][3][ol];
        atomicAdd(&latf[bb * 768 + o], v);
    }
}

// ---------------------------------------------------------------- GEMM (m97 structure)
// C[M,N] = A[M,K] @ Bt[N,K]^T ; 128xTN tile, BK=32, 4 waves, 16x16x32 bf16 MFMA.
// EPI 0: +bias -> bf16 qkv for cols<1536; V-cols (>=1536) go ONLY to vT[bh][d][s].
// EPI 1: (acc+bias)*latf*(0.125*log2e) -> bf16 (fused q)   EPI 2: +bias -> f32
template <int EPI, int TN>
__global__ __launch_bounds__(256) void gemm_bt(
    const bf16* __restrict__ A, int lda, const bf16* __restrict__ Bt,
    const float* __restrict__ bias, const float* __restrict__ latf,
    void* __restrict__ Cout, bf16* __restrict__ vTout, int ldc, int K) {
    constexpr int FN = TN / 32;
    __shared__ bf16 Al[128 * 32];
    __shared__ bf16 Bl[TN * 32];
    const int tid = threadIdx.x, w = tid >> 6, lane = tid & 63;
    const int row0 = blockIdx.x * 128, col0 = blockIdx.y * TN;
    const int wm = (w >> 1) * 64, wn = (w & 1) * (TN / 2);
    const int lr = lane & 15, lk8 = (lane >> 4) * 8, lq = lane >> 4;
    const int sr = lane >> 2;
    const int sc = (lane & 3) * 8;
    f32x4 acc[4][FN] = {};
    for (int k0 = 0; k0 < K; k0 += 32) {
#pragma unroll
        for (int i = 0; i < 2; ++i) {
            const int rr = w * 32 + i * 16;
            gload_lds16(A + (size_t)(row0 + rr + sr) * lda + k0 + sc, &Al[rr * 32]);
        }
#pragma unroll
        for (int i = 0; i < TN / 64; ++i) {
            const int rb = (w * (TN / 64) + i) * 16;
            gload_lds16(Bt + (size_t)(col0 + rb + sr) * K + k0 + sc, &Bl[rb * 32]);
        }
        __syncthreads();
        s16x8 af[4], bfr[FN];
#pragma unroll
        for (int m = 0; m < 4; ++m) af[m]  = *(const s16x8*)&Al[(wm + m * 16 + lr) * 32 + lk8];
#pragma unroll
        for (int n = 0; n < FN; ++n) bfr[n] = *(const s16x8*)&Bl[(wn + n * 16 + lr) * 32 + lk8];
        __builtin_amdgcn_s_setprio(1);
#pragma unroll
        for (int m = 0; m < 4; ++m)
#pragma unroll
            for (int n = 0; n < FN; ++n)
                acc[m][n] = __builtin_amdgcn_mfma_f32_16x16x32_bf16(af[m], bfr[n], acc[m][n], 0, 0, 0);
        __builtin_amdgcn_s_setprio(0);
        __syncthreads();
    }
#pragma unroll
    for (int m = 0; m < 4; ++m)
#pragma unroll
        for (int n = 0; n < FN; ++n) {
            const int rowb = row0 + wm + m * 16 + lq * 4;  // r spans rowb..rowb+3
            const int col  = col0 + wn + n * 16 + lr;
            if (EPI == 0 && col0 >= 1536) {
                // V region: write only vT[bh][d][s] (packed over r = consecutive s)
                const int vcol = col - 1536;
                s16x4 vo;
#pragma unroll
                for (int r = 0; r < 4; ++r) vo[r] = f2bf(acc[m][n][r] + bias[col]);
                bf16* vdst = vTout +
                    ((size_t)((rowb >> 11) * 12 + (vcol >> 6)) * 64 + (vcol & 63)) * 2048 +
                    (rowb & 2047);
                *(s16x4*)vdst = vo;
            } else {
#pragma unroll
                for (int r = 0; r < 4; ++r) {
                    const int row = rowb + r;
                    const float v = acc[m][n][r];
                    if (EPI == 0) {
                        ((bf16*)Cout)[(size_t)row * ldc + col] = __float2bfloat16(v + bias[col]);
                    } else if (EPI == 1) {
                        ((bf16*)Cout)[(size_t)row * ldc + col] = __float2bfloat16(
                            (v + bias[col]) * latf[(row >> 11) * 768 + col] * 0.18033688011112042f);
                    } else {
                        ((float*)Cout)[(size_t)row * ldc + col] = v + bias[col];
                    }
                }
            }
        }
}

// ---------------------------------------------------------------- flash attention
// 192 blocks (24 bh x 8 pairs, XCD-grouped: 3 heads per XCD) x 8 waves (512 thr).
// Block runs TWO q-tiles sequentially: light [128p,128p+128) over L=2p+2 KV tiles,
// heavy [2048-128(p+1), ..+128) over H=32-2p tiles => uniform 34 stage-iters/block.
// Each wave owns 16 q-rows/phase. K (64x64) and V^T (64x64) LDS-staged per tile via
// global_load_lds, double-buffered, XOR-swizzled (linear LDS dest + pre-swizzled
// per-lane global src, swizzled ds_read — rule #21). One __syncthreads per tile
// (its vmcnt(0)+lgkmcnt(0) drain is exactly the needed fence). Swapped QK^T:
// lane owns q-row (lr); softmax = in-lane max + 2 shfl; P via per-wave LDS;
// PV: O^T = mfma(V^T, P^T). exp2 domain (log2e*0.125 folded into qf).
__global__ __launch_bounds__(512, 2) void attn_k(
    const bf16* __restrict__ qf, const bf16* __restrict__ qkv,
    const bf16* __restrict__ vT, bf16* __restrict__ aout) {
    __shared__ bf16 KL[2][4096];
    __shared__ bf16 VL[2][4096];
    __shared__ unsigned short Pl[8][16][68];
    const int w = threadIdx.x >> 6, lane = threadIdx.x & 63;
    // 192 blocks: xcd = blk&7 gets 3 heads; p = pair index
    const int bh = (blockIdx.x & 7) * 3 + (blockIdx.x >> 3) / 8;
    const int p  = (blockIdx.x >> 3) & 7;
    const int b = bh / 12, h = bh - b * 12;
    const int lr = lane & 15, lq = lane >> 4;
    // staging lane mapping: row = 8w + (lane>>3), chunk = (lane&7) ^ ((lane>>3)&7)
    const int sw_row = 8 * w + (lane >> 3);
    const int sw_ck  = (lane & 7) ^ ((lane >> 3) & 7);
    const bf16* Kg = qkv + (size_t)b * 2048 * 2304 + 768 + h * 64;  // rows = keys
    const bf16* Vg = vT + (size_t)bh * 64 * 2048;                   // rows = d

    auto STAGE = [&](int t, int buf) {
        const int kv0s = t * 64;
        gload_lds16(Kg + (size_t)(kv0s + sw_row) * 2304 + sw_ck * 8, &KL[buf][w * 512]);
        gload_lds16(Vg + (size_t)sw_row * 2048 + kv0s + sw_ck * 8, &VL[buf][w * 512]);
    };

#pragma unroll 1
    for (int ph = 0; ph < 2; ++ph) {
        const int qpos0 = ph ? 2048 - 128 * (p + 1) : 128 * p;
        const int T     = ph ? 32 - 2 * p : 2 * p + 2;
        const int qw    = qpos0 + 16 * w;        // wave's first q-row (seq pos)
        const size_t grow = (size_t)b * 2048 + qw;
        s16x8 qa0, qa1;
        {
            const bf16* qp = qf + (grow + lr) * 768 + h * 64 + lq * 8;
            qa0 = *(const s16x8*)qp;
            qa1 = *(const s16x8*)(qp + 32);
        }
        float mr = -3.0e38f, lsum = 0.f;
        f32x4 oacc[4] = {};
        int myT = (qw + 79) >> 6;
        if (myT > T) myT = T;
        STAGE(0, 0);
        __syncthreads();
        for (int t = 0; t < T; ++t) {
            const int cur = t & 1;
            if (t + 1 < T) STAGE(t + 1, cur ^ 1);
            if (t < myT) {
                const int kv0 = t * 64;
                f32x4 st[4] = {};
                __builtin_amdgcn_s_setprio(1);
#pragma unroll
                for (int ks = 0; ks < 2; ++ks) {
                    const int ck = ((4 * ks + lq) ^ (lr & 7)) * 8;
                    const s16x8 qa = ks ? qa1 : qa0;
#pragma unroll
                    for (int n = 0; n < 4; ++n) {
                        s16x8 kb = *(const s16x8*)&KL[cur][(n * 16 + lr) * 64 + ck];
                        st[n] = __builtin_amdgcn_mfma_f32_16x16x32_bf16(kb, qa, st[n], 0, 0, 0);
                    }
                }
                __builtin_amdgcn_s_setprio(0);
                if (kv0 + 63 > qw) {  // diagonal tile(s): causal mask
#pragma unroll
                    for (int n = 0; n < 4; ++n)
#pragma unroll
                        for (int r = 0; r < 4; ++r)
                            if (kv0 + n * 16 + lq * 4 + r > qw + lr) st[n][r] = -10000.f;
                }
                // online softmax (exp2 domain); lane owns row q=lr
                f32x4 m4 = vmax4(vmax4(st[0], st[1]), vmax4(st[2], st[3]));
                float v = fmaxf(fmaxf(m4[0], m4[1]), fmaxf(m4[2], m4[3]));
                v = fmaxf(v, __shfl_xor(v, 16));
                v = fmaxf(v, __shfl_xor(v, 32));
                const float newm = fmaxf(mr, v);
                const float scl = __builtin_amdgcn_exp2f(mr - newm);
                mr = newm;
#pragma unroll
                for (int n = 0; n < 4; ++n)
#pragma unroll
                    for (int e = 0; e < 4; ++e)
                        st[n][e] = __builtin_amdgcn_exp2f(st[n][e] - newm);
                f32x4 ps4 = (st[0] + st[1]) + (st[2] + st[3]);
                lsum = lsum * scl + ((ps4[0] + ps4[1]) + (ps4[2] + ps4[3]));
#pragma unroll
                for (int dn = 0; dn < 4; ++dn) oacc[dn] *= scl;
                // P -> per-wave LDS (transpose to B-fragment layout)
#pragma unroll
                for (int n = 0; n < 4; ++n) {
                    s16x4 pk;
#pragma unroll
                    for (int r = 0; r < 4; ++r) pk[r] = f2bf(st[n][r]);
                    *(s16x4*)&Pl[w][lr][n * 16 + lq * 4] = pk;
                }
                __builtin_amdgcn_s_setprio(1);
#pragma unroll
                for (int ks = 0; ks < 2; ++ks) {
                    const s16x8 pb = *(const s16x8*)&Pl[w][lr][ks * 32 + lq * 8];
                    const int ck = ((4 * ks + lq) ^ (lr & 7)) * 8;
#pragma unroll
                    for (int dn = 0; dn < 4; ++dn) {
                        s16x8 vb = *(const s16x8*)&VL[cur][(dn * 16 + lr) * 64 + ck];
                        oacc[dn] = __builtin_amdgcn_mfma_f32_16x16x32_bf16(vb, pb, oacc[dn], 0, 0, 0);
                    }
                }
                __builtin_amdgcn_s_setprio(0);
            }
            __syncthreads();
        }
        lsum += __shfl_xor(lsum, 16);
        lsum += __shfl_xor(lsum, 32);
        const float inv = 1.0f / lsum;
#pragma unroll
        for (int dn = 0; dn < 4; ++dn) {
            s16x4 o4;
#pragma unroll
            for (int r = 0; r < 4; ++r) o4[r] = f2bf(oacc[dn][r] * inv);
            *(s16x4*)&aout[(grow + lr) * 768 + h * 64 + dn * 16 + lq * 4] = o4;
        }
    }
}

// ---------------------------------------------------------------- launch

extern "C" void kernel_launch(void* const* d_in, const int* in_sizes, int n_in,
                              void* d_out, int out_size, void* d_ws, size_t ws_size,
                              hipStream_t stream) {
    (void)in_sizes; (void)n_in; (void)out_size; (void)ws_size;
    const float* x      = (const float*)d_in[0];
    const float* lat    = (const float*)d_in[1];
    const float* attn_w = (const float*)d_in[2];
    const float* attn_b = (const float*)d_in[3];
    const float* proj_w = (const float*)d_in[4];
    const float* proj_b = (const float*)d_in[5];
    const float* text_w = (const float*)d_in[6];
    const float* text_b = (const float*)d_in[7];
    const float* lat_w  = (const float*)d_in[8];
    const float* lat_b  = (const float*)d_in[9];
    float* out = (float*)d_out;

    char* ws = (char*)d_ws;
    size_t off = 0;
    auto take = [&](size_t bytes) -> char* {
        char* p = ws + off;
        off = (off + bytes + 255) & ~(size_t)255;
        return p;
    };
    bf16* x_bf   = (bf16*)take(4096ul * 768 * 2);
    bf16* awT    = (bf16*)take(2304ul * 768 * 2);
    bf16* pwT    = (bf16*)take(768ul * 768 * 2);
    bf16* twT    = (bf16*)take(768ul * 768 * 2);
    bf16* qkv_bf = (bf16*)take(4096ul * 2304 * 2);
    bf16* qf_bf  = (bf16*)take(4096ul * 768 * 2);
    bf16* vT     = (bf16*)take(24ul * 64 * 2048 * 2);
    bf16* a_bf   = (bf16*)take(4096ul * 768 * 2);
    float* tbias = (float*)take(768 * 4);
    float* latf  = (float*)take(2 * 768 * 4);

    prep_all<<<dim3(72, 24, 5), 256, 0, stream>>>(x, attn_w, proj_w, text_w, text_b,
                                                  lat, lat_w, lat_b, x_bf, awT, pwT,
                                                  twT, tbias, latf);
    latf_partial<<<dim3(12, 8), 256, 0, stream>>>(lat, lat_w, latf);
    gemm_bt<0, 128><<<dim3(32, 18), 256, 0, stream>>>(x_bf, 768, awT, attn_b, nullptr,
                                                      qkv_bf, vT, 2304, 768);
    gemm_bt<1, 64><<<dim3(32, 12), 256, 0, stream>>>(qkv_bf, 2304, twT, tbias, latf,
                                                     qf_bf, nullptr, 768, 768);
    attn_k<<<192, 512, 0, stream>>>(qf_bf, qkv_bf, vT, a_bf);
    gemm_bt<2, 64><<<dim3(32, 12), 256, 0, stream>>>(a_bf, 768, pwT, proj_b, nullptr,
                                                     out, nullptr, 768, 768);
}

// Round 11
// 202.297 us; speedup vs baseline: 1.6695x; 1.0292x over previous
//
#include <hip/hip_runtime.h>
#include <hip/hip_bf16.h>
#include <cstdint>

#define DEV __device__ __forceinline__

typedef short  s16x8 __attribute__((ext_vector_type(8)));
typedef short  s16x4 __attribute__((ext_vector_type(4)));
typedef unsigned short u16x8 __attribute__((ext_vector_type(8)));
typedef float  f32x4 __attribute__((ext_vector_type(4)));
typedef __hip_bfloat16 bf16;

DEV short f2bf(float f) {
    __hip_bfloat16 h = __float2bfloat16(f);
    return __builtin_bit_cast(short, h);
}

DEV f32x4 vmax4(f32x4 a, f32x4 b) {
    f32x4 r;
#pragma unroll
    for (int j = 0; j < 4; ++j) r[j] = fmaxf(a[j], b[j]);
    return r;
}

// global -> LDS async copy, 16B per lane; LDS base must be wave-uniform.
DEV void gload_lds16(const void* g, void* l) {
    __builtin_amdgcn_global_load_lds(
        (const __attribute__((address_space(1))) uint32_t*)g,
        (__attribute__((address_space(3))) uint32_t*)l, 16, 0, 0);
}

// ---------------------------------------------------------------- prep (one launch)
// z=0: attn_w^T (768x2304->T)  z=1: proj_w^T  z=2: sum_r text_w^T
// z=3: bias_text (x<3) + latf INIT (3<=x<9: bias+ones-row terms)  z=4: x fp32->bf16
__global__ void prep_all(const float* __restrict__ x, const float* __restrict__ aw,
                         const float* __restrict__ pw, const float* __restrict__ tw,
                         const float* __restrict__ tb, const float* __restrict__ lat,
                         const float* __restrict__ lw, const float* __restrict__ lb,
                         bf16* __restrict__ x_bf, bf16* __restrict__ awT,
                         bf16* __restrict__ pwT, bf16* __restrict__ twT,
                         float* __restrict__ tbias, float* __restrict__ latf) {
    const int z = blockIdx.z;
    if (z == 4) {  // convert x
        const int idx = blockIdx.y * 72 + blockIdx.x;
        if (idx >= 1536) return;
        const int i = (idx * 256 + threadIdx.x) * 8;
        f32x4 a = *(const f32x4*)&x[i];
        f32x4 c = *(const f32x4*)&x[i + 4];
        u16x8 o;
#pragma unroll
        for (int j = 0; j < 4; ++j) {
            o[j]     = (unsigned short)f2bf(a[j]);
            o[4 + j] = (unsigned short)f2bf(c[j]);
        }
        *(u16x8*)&x_bf[i] = o;
        return;
    }
    if (z == 3) {
        if (blockIdx.y != 0) return;
        const int xk = blockIdx.x;
        if (xk < 3) {  // bias_text
            const int o = xk * 256 + threadIdx.x;
            float s = 0.f;
#pragma unroll
            for (int r = 0; r < 4; ++r)
                s += tw[((size_t)r * 769 + 768) * 768 + o] + tb[r * 768 + o];
            tbias[o] = s;
        } else if (xk < 9) {  // latf init: ones-row of lat_w + summed bias
            const int idx = (xk - 3) * 256 + threadIdx.x;  // 0..1535
            const int bb = idx >= 768 ? 1 : 0;
            const int o = idx - bb * 768;
            float s = 0.f;
#pragma unroll
            for (int r = 0; r < 4; ++r)
                s += lw[((size_t)r * 769 + 768) * 768 + o] + lb[r * 768 + o];
            latf[bb * 768 + o] = s;
        }
        return;
    }
    // transposes
    __shared__ float t[32][33];
    const float* in; bf16* out; int C, G; size_t rstr;
    if (z == 0)      { in = aw; out = awT; C = 2304; G = 1; rstr = 0; }
    else if (z == 1) { in = pw; out = pwT; C = 768;  G = 1; rstr = 0; }
    else             { in = tw; out = twT; C = 768;  G = 4; rstr = 769ul * 768; }
    const int c0 = blockIdx.x * 32, r0 = blockIdx.y * 32;
    if (c0 >= C) return;
    const int tx = threadIdx.x & 31, ty = threadIdx.x >> 5;
#pragma unroll
    for (int i = 0; i < 32; i += 8) {
        float s = 0.f;
        for (int g = 0; g < G; ++g)
            s += in[g * rstr + (size_t)(r0 + ty + i) * C + c0 + tx];
        t[ty + i][tx] = s;
    }
    __syncthreads();
#pragma unroll
    for (int i = 0; i < 32; i += 8)
        out[(size_t)(c0 + ty + i) * 768 + r0 + tx] = __float2bfloat16(t[tx][ty + i]);
}

// latf accumulation: latf[b][o] += sum_{i<768} lat[b][i] * sum_r lat_w[r][i][o].
// grid (12 o-chunks of 64, 8 i-chunks of 96); o coalesced across lanes; lw read
// once per block, used for both b; LDS partial-reduce, 1 atomicAdd per (b,o).
__global__ __launch_bounds__(256) void latf_partial(
    const float* __restrict__ lat, const float* __restrict__ lw,
    float* __restrict__ latf) {
    const int oc = blockIdx.x, ic = blockIdx.y;
    const int ol = threadIdx.x & 63, wv = threadIdx.x >> 6;
    const int o = oc * 64 + ol;
    float s0 = 0.f, s1 = 0.f;
#pragma unroll 4
    for (int t = 0; t < 24; ++t) {
        const int i = ic * 96 + wv * 24 + t;
        float wsum = 0.f;
#pragma unroll
        for (int r = 0; r < 4; ++r) wsum += lw[((size_t)r * 769 + i) * 768 + o];
        s0 += lat[i] * wsum;
        s1 += lat[768 + i] * wsum;
    }
    __shared__ float ps[2][4][64];
    ps[0][wv][ol] = s0;
    ps[1][wv][ol] = s1;
    __syncthreads();
    if (threadIdx.x < 128) {
        const int bb = threadIdx.x >> 6;
        float v = ps[bb][0][ol] + ps[bb][1][ol] + ps[bb][2][ol] + ps[bb][3][ol];
        atomicAdd(&latf[bb * 768 + o], v);
    }
}

// ---------------------------------------------------------------- GEMM (m97 structure)
// C[M,N] = A[M,K] @ Bt[N,K]^T ; 128xTN tile, BK=32, 4 waves, 16x16x32 bf16 MFMA.
// EPI 0: +bias -> bf16 qkv for cols<1536; V-cols (>=1536) go ONLY to vT[bh][d][s].
// EPI 1: (acc+bias)*latf*(0.125*log2e) -> bf16 (fused q)   EPI 2: +bias -> f32
template <int EPI, int TN>
__global__ __launch_bounds__(256) void gemm_bt(
    const bf16* __restrict__ A, int lda, const bf16* __restrict__ Bt,
    const float* __restrict__ bias, const float* __restrict__ latf,
    void* __restrict__ Cout, bf16* __restrict__ vTout, int ldc, int K) {
    constexpr int FN = TN / 32;
    __shared__ bf16 Al[128 * 32];
    __shared__ bf16 Bl[TN * 32];
    const int tid = threadIdx.x, w = tid >> 6, lane = tid & 63;
    const int row0 = blockIdx.x * 128, col0 = blockIdx.y * TN;
    const int wm = (w >> 1) * 64, wn = (w & 1) * (TN / 2);
    const int lr = lane & 15, lk8 = (lane >> 4) * 8, lq = lane >> 4;
    const int sr = lane >> 2;
    const int sc = (lane & 3) * 8;
    f32x4 acc[4][FN] = {};
    for (int k0 = 0; k0 < K; k0 += 32) {
#pragma unroll
        for (int i = 0; i < 2; ++i) {
            const int rr = w * 32 + i * 16;
            gload_lds16(A + (size_t)(row0 + rr + sr) * lda + k0 + sc, &Al[rr * 32]);
        }
#pragma unroll
        for (int i = 0; i < TN / 64; ++i) {
            const int rb = (w * (TN / 64) + i) * 16;
            gload_lds16(Bt + (size_t)(col0 + rb + sr) * K + k0 + sc, &Bl[rb * 32]);
        }
        __syncthreads();
        s16x8 af[4], bfr[FN];
#pragma unroll
        for (int m = 0; m < 4; ++m) af[m]  = *(const s16x8*)&Al[(wm + m * 16 + lr) * 32 + lk8];
#pragma unroll
        for (int n = 0; n < FN; ++n) bfr[n] = *(const s16x8*)&Bl[(wn + n * 16 + lr) * 32 + lk8];
        __builtin_amdgcn_s_setprio(1);
#pragma unroll
        for (int m = 0; m < 4; ++m)
#pragma unroll
            for (int n = 0; n < FN; ++n)
                acc[m][n] = __builtin_amdgcn_mfma_f32_16x16x32_bf16(af[m], bfr[n], acc[m][n], 0, 0, 0);
        __builtin_amdgcn_s_setprio(0);
        __syncthreads();
    }
#pragma unroll
    for (int m = 0; m < 4; ++m)
#pragma unroll
        for (int n = 0; n < FN; ++n) {
            const int rowb = row0 + wm + m * 16 + lq * 4;  // r spans rowb..rowb+3
            const int col  = col0 + wn + n * 16 + lr;
            if (EPI == 0 && col0 >= 1536) {
                // V region: write only vT[bh][d][s] (packed over r = consecutive s)
                const int vcol = col - 1536;
                s16x4 vo;
#pragma unroll
                for (int r = 0; r < 4; ++r) vo[r] = f2bf(acc[m][n][r] + bias[col]);
                bf16* vdst = vTout +
                    ((size_t)((rowb >> 11) * 12 + (vcol >> 6)) * 64 + (vcol & 63)) * 2048 +
                    (rowb & 2047);
                *(s16x4*)vdst = vo;
            } else {
#pragma unroll
                for (int r = 0; r < 4; ++r) {
                    const int row = rowb + r;
                    const float v = acc[m][n][r];
                    if (EPI == 0) {
                        ((bf16*)Cout)[(size_t)row * ldc + col] = __float2bfloat16(v + bias[col]);
                    } else if (EPI == 1) {
                        ((bf16*)Cout)[(size_t)row * ldc + col] = __float2bfloat16(
                            (v + bias[col]) * latf[(row >> 11) * 768 + col] * 0.18033688011112042f);
                    } else {
                        ((float*)Cout)[(size_t)row * ldc + col] = v + bias[col];
                    }
                }
            }
        }
}

// ---------------------------------------------------------------- flash attention
// 768 blocks x 4 waves (256 thr): block = one 64-row q-tile of one (b,h).
// LPT dispatch: tile p = 31 - blk/24 (heavy first, light tiles pack the tail);
// bh = blk%24 and 24%8==0 => all blocks of a head land on the SAME XCD (L2 reuse).
// T = p+1 stage-iterations; 3 blocks/CU co-resident (LDS 41KB) so the per-barrier
// vmcnt drain of one block overlaps compute of the other two (m114 effect).
// K (64x64) and V^T (64x64) LDS-staged double-buffered via global_load_lds,
// XOR-swizzled (linear LDS dest + pre-swizzled global src + swizzled ds_read).
// Swapped QK^T: lane owns q-row (lr); softmax = in-lane max + 2 shfl; P via
// per-wave LDS; PV: O^T = mfma(V^T, P^T). exp2 domain (log2e*0.125 in qf).
__global__ __launch_bounds__(256, 3) void attn_k(
    const bf16* __restrict__ qf, const bf16* __restrict__ qkv,
    const bf16* __restrict__ vT, bf16* __restrict__ aout) {
    __shared__ bf16 KL[2][4096];
    __shared__ bf16 VL[2][4096];
    __shared__ unsigned short Pl[4][16][68];
    const int w = threadIdx.x >> 6, lane = threadIdx.x & 63;
    const int bh = blockIdx.x % 24;          // same XCD for all blocks of a head
    const int p  = 31 - blockIdx.x / 24;     // heavy tiles dispatch first (LPT)
    const int b = bh / 12, h = bh - b * 12;
    const int lr = lane & 15, lq = lane >> 4;
    // staging: 256 threads cover 32 rows x 8 chunks per issue; 2 issues per tile.
    // row r slot c holds global chunk c^(r&7) (XOR swizzle, linear LDS dest).
    const int st_row = threadIdx.x >> 3;                    // 0..31
    const int st_ck  = (threadIdx.x & 7) ^ (st_row & 7);    // pre-swizzled source
    const bf16* Kg = qkv + (size_t)b * 2048 * 2304 + 768 + h * 64;  // rows = keys
    const bf16* Vg = vT + (size_t)bh * 64 * 2048;                   // rows = d

    auto STAGE = [&](int t, int buf) {
        const int kv0s = t * 64;
#pragma unroll
        for (int half = 0; half < 2; ++half) {
            const int r0 = half * 32;  // wave-uniform LDS chunk: rows r0+8w..r0+8w+7
            gload_lds16(Kg + (size_t)(kv0s + r0 + st_row) * 2304 + st_ck * 8,
                        &KL[buf][(r0 + 8 * w) * 64]);
            gload_lds16(Vg + (size_t)(r0 + st_row) * 2048 + kv0s + st_ck * 8,
                        &VL[buf][(r0 + 8 * w) * 64]);
        }
    };

    const int qw = 64 * p + 16 * w;          // wave's first q-row (seq pos)
    const size_t grow = (size_t)b * 2048 + qw;
    s16x8 qa0, qa1;
    {
        const bf16* qp = qf + (grow + lr) * 768 + h * 64 + lq * 8;
        qa0 = *(const s16x8*)qp;
        qa1 = *(const s16x8*)(qp + 32);
    }
    float mr = -3.0e38f, lsum = 0.f;
    f32x4 oacc[4] = {};
    const int T = p + 1;
    int myT = (qw + 79) >> 6;
    if (myT > T) myT = T;
    STAGE(0, 0);
    __syncthreads();
    for (int t = 0; t < T; ++t) {
        const int cur = t & 1;
        if (t + 1 < T) STAGE(t + 1, cur ^ 1);
        if (t < myT) {
            const int kv0 = t * 64;
            f32x4 st[4] = {};
            __builtin_amdgcn_s_setprio(1);
#pragma unroll
            for (int ks = 0; ks < 2; ++ks) {
                const int ck = ((4 * ks + lq) ^ (lr & 7)) * 8;
                const s16x8 qa = ks ? qa1 : qa0;
#pragma unroll
                for (int n = 0; n < 4; ++n) {
                    s16x8 kb = *(const s16x8*)&KL[cur][(n * 16 + lr) * 64 + ck];
                    st[n] = __builtin_amdgcn_mfma_f32_16x16x32_bf16(kb, qa, st[n], 0, 0, 0);
                }
            }
            __builtin_amdgcn_s_setprio(0);
            if (kv0 + 63 > qw) {  // diagonal tile(s): causal mask
#pragma unroll
                for (int n = 0; n < 4; ++n)
#pragma unroll
                    for (int r = 0; r < 4; ++r)
                        if (kv0 + n * 16 + lq * 4 + r > qw + lr) st[n][r] = -10000.f;
            }
            // online softmax (exp2 domain); lane owns row q=lr
            f32x4 m4 = vmax4(vmax4(st[0], st[1]), vmax4(st[2], st[3]));
            float v = fmaxf(fmaxf(m4[0], m4[1]), fmaxf(m4[2], m4[3]));
            v = fmaxf(v, __shfl_xor(v, 16));
            v = fmaxf(v, __shfl_xor(v, 32));
            const float newm = fmaxf(mr, v);
            const float scl = __builtin_amdgcn_exp2f(mr - newm);
            mr = newm;
#pragma unroll
            for (int n = 0; n < 4; ++n)
#pragma unroll
                for (int e = 0; e < 4; ++e)
                    st[n][e] = __builtin_amdgcn_exp2f(st[n][e] - newm);
            f32x4 ps4 = (st[0] + st[1]) + (st[2] + st[3]);
            lsum = lsum * scl + ((ps4[0] + ps4[1]) + (ps4[2] + ps4[3]));
#pragma unroll
            for (int dn = 0; dn < 4; ++dn) oacc[dn] *= scl;
            // P -> per-wave LDS (transpose to B-fragment layout)
#pragma unroll
            for (int n = 0; n < 4; ++n) {
                s16x4 pk;
#pragma unroll
                for (int r = 0; r < 4; ++r) pk[r] = f2bf(st[n][r]);
                *(s16x4*)&Pl[w][lr][n * 16 + lq * 4] = pk;
            }
            __builtin_amdgcn_s_setprio(1);
#pragma unroll
            for (int ks = 0; ks < 2; ++ks) {
                const s16x8 pb = *(const s16x8*)&Pl[w][lr][ks * 32 + lq * 8];
                const int ck = ((4 * ks + lq) ^ (lr & 7)) * 8;
#pragma unroll
                for (int dn = 0; dn < 4; ++dn) {
                    s16x8 vb = *(const s16x8*)&VL[cur][(dn * 16 + lr) * 64 + ck];
                    oacc[dn] = __builtin_amdgcn_mfma_f32_16x16x32_bf16(vb, pb, oacc[dn], 0, 0, 0);
                }
            }
            __builtin_amdgcn_s_setprio(0);
        }
        __syncthreads();
    }
    lsum += __shfl_xor(lsum, 16);
    lsum += __shfl_xor(lsum, 32);
    const float inv = 1.0f / lsum;
#pragma unroll
    for (int dn = 0; dn < 4; ++dn) {
        s16x4 o4;
#pragma unroll
        for (int r = 0; r < 4; ++r) o4[r] = f2bf(oacc[dn][r] * inv);
        *(s16x4*)&aout[(grow + lr) * 768 + h * 64 + dn * 16 + lq * 4] = o4;
    }
}

// ---------------------------------------------------------------- launch

extern "C" void kernel_launch(void* const* d_in, const int* in_sizes, int n_in,
                              void* d_out, int out_size, void* d_ws, size_t ws_size,
                              hipStream_t stream) {
    (void)in_sizes; (void)n_in; (void)out_size; (void)ws_size;
    const float* x      = (const float*)d_in[0];
    const float* lat    = (const float*)d_in[1];
    const float* attn_w = (const float*)d_in[2];
    const float* attn_b = (const float*)d_in[3];
    const float* proj_w = (const float*)d_in[4];
    const float* proj_b = (const float*)d_in[5];
    const float* text_w = (const float*)d_in[6];
    const float* text_b = (const float*)d_in[7];
    const float* lat_w  = (const float*)d_in[8];
    const float* lat_b  = (const float*)d_in[9];
    float* out = (float*)d_out;

    char* ws = (char*)d_ws;
    size_t off = 0;
    auto take = [&](size_t bytes) -> char* {
        char* p = ws + off;
        off = (off + bytes + 255) & ~(size_t)255;
        return p;
    };
    bf16* x_bf   = (bf16*)take(4096ul * 768 * 2);
    bf16* awT    = (bf16*)take(2304ul * 768 * 2);
    bf16* pwT    = (bf16*)take(768ul * 768 * 2);
    bf16* twT    = (bf16*)take(768ul * 768 * 2);
    bf16* qkv_bf = (bf16*)take(4096ul * 2304 * 2);
    bf16* qf_bf  = (bf16*)take(4096ul * 768 * 2);
    bf16* vT     = (bf16*)take(24ul * 64 * 2048 * 2);
    bf16* a_bf   = (bf16*)take(4096ul * 768 * 2);
    float* tbias = (float*)take(768 * 4);
    float* latf  = (float*)take(2 * 768 * 4);

    prep_all<<<dim3(72, 24, 5), 256, 0, stream>>>(x, attn_w, proj_w, text_w, text_b,
                                                  lat, lat_w, lat_b, x_bf, awT, pwT,
                                                  twT, tbias, latf);
    latf_partial<<<dim3(12, 8), 256, 0, stream>>>(lat, lat_w, latf);
    gemm_bt<0, 128><<<dim3(32, 18), 256, 0, stream>>>(x_bf, 768, awT, attn_b, nullptr,
                                                      qkv_bf, vT, 2304, 768);
    gemm_bt<1, 64><<<dim3(32, 12), 256, 0, stream>>>(qkv_bf, 2304, twT, tbias, latf,
                                                     qf_bf, nullptr, 768, 768);
    attn_k<<<768, 256, 0, stream>>>(qf_bf, qkv_bf, vT, a_bf);
    gemm_bt<2, 64><<<dim3(32, 12), 256, 0, stream>>>(a_bf, 768, pwT, proj_b, nullptr,
                                                     out, nullptr, 768, 768);
}